// Round 2
// baseline (12439.091 us; speedup 1.0000x reference)
//
#include <hip/hip_runtime.h>

#define DEV __device__ __forceinline__

// ---------------------------------------------------------------------------
// TernaryMVAdapter forward on MI355X. Round 1: f64-exact quantization
// decisions (weight ternary + act int8 + row stats) on top of the round-0
// structure. Reference is evaluated in f64; all rounding decisions are now
// computed in double so the only divergence is unavoidable f32 GEMM noise.
//
// Structural simplifications (output-equivalent):
//  * SA blocks 1,2 are dead code (only feats[0] is consumed)  -> skipped
//  * ref_rep rows repeat 4x -> ref attention computed on 2 unique batches
//  * mv attention = permutation of xm tokens -> only the scan walks view order
//  * wi/wf/wg share one rmsnorm+quant; silu(c) quant shared by both blocks+final
// ---------------------------------------------------------------------------

// ---------------- deterministic |w| sum (two-stage, f64) -------------------
__global__ void k_abssum_part(const float* __restrict__ w, long long n,
                              double* __restrict__ partial)
{
    __shared__ double sm[256];
    double s = 0.0;
    for (long long i = (long long)blockIdx.x*blockDim.x + threadIdx.x; i < n;
         i += (long long)gridDim.x*blockDim.x)
        s += (double)fabsf(w[i]);
    sm[threadIdx.x] = s;
    __syncthreads();
    for (int k = 128; k > 0; k >>= 1) {
        if ((int)threadIdx.x < k) sm[threadIdx.x] += sm[threadIdx.x + k];
        __syncthreads();
    }
    if (threadIdx.x == 0) partial[blockIdx.x] = sm[0];
}

__global__ void k_abssum_fin(const double* __restrict__ partial, double* __restrict__ out)
{
    __shared__ double sm[512];
    sm[threadIdx.x] = partial[threadIdx.x];
    __syncthreads();
    for (int k = 256; k > 0; k >>= 1) {
        if ((int)threadIdx.x < k) sm[threadIdx.x] += sm[threadIdx.x + k];
        __syncthreads();
    }
    if (threadIdx.x == 0) out[0] = sm[0];
}

// ---------------- timestep frequency embedding (f64) -----------------------
__global__ void k_temb(const float* __restrict__ t, float* __restrict__ out)
{
    int b = blockIdx.x, j = threadIdx.x;               // 8 x 128
    double fr  = exp(-9.210340371976184 * (double)j / 128.0);
    double ang = (double)t[b] * fr;
    out[b*256 + j]       = (float)cos(ang);
    out[b*256 + 128 + j] = (float)sin(ang);
}

// ---------------- rmsnorm + int8 absmax act quant (per row, f64 stats) -----
// out = clip(round(xn*s),-128,127)/s,  xn = x*rsqrt(mean(x^2)+1e-8),
// s = 127/max(amax(|xn|),1e-5).  Optional silu applied to input first.
__global__ void k_rsq(const float* __restrict__ x, float* __restrict__ out,
                      int K, int pre_silu)
{
    extern __shared__ double rb[];
    __shared__ double red[256], red2[256];
    const int row = blockIdx.x, tid = threadIdx.x;
    const float* xr = x + (size_t)row*K;
    double ss = 0.0, am = 0.0;
    for (int i = tid; i < K; i += 256) {
        double v = (double)xr[i];
        if (pre_silu) v = v / (1.0 + exp(-v));         // silu in f64
        rb[i] = v; ss += v*v; am = fmax(am, fabs(v));
    }
    red[tid] = ss; red2[tid] = am;
    __syncthreads();
    for (int s = 128; s > 0; s >>= 1) {
        if (tid < s) { red[tid] += red[tid+s]; red2[tid] = fmax(red2[tid], red2[tid+s]); }
        __syncthreads();
    }
    double rms = 1.0 / sqrt(red[0]/(double)K + 1e-8);
    double s   = 127.0 / fmax(red2[0]*rms, 1e-5);
    float* orow = out + (size_t)row*K;
    for (int i = tid; i < K; i += 256) {
        double q = fmin(fmax(rint(rb[i]*rms*s), -128.0), 127.0);
        orow[i] = (float)(q / s);
    }
}

// ---------------- layernorm (+optional gamma/beta, +optional modulate) -----
__global__ void k_ln(const float* __restrict__ x, float* __restrict__ out, int K,
                     const float* __restrict__ gamma, const float* __restrict__ beta,
                     const float* __restrict__ sh, const float* __restrict__ sc,
                     int modstride, int rows_per_bn, float eps)
{
    extern __shared__ double rb[];
    __shared__ double red[256];
    const int row = blockIdx.x, tid = threadIdx.x;
    const float* xr = x + (size_t)row*K;
    double s1 = 0.0;
    for (int i = tid; i < K; i += 256) { double v = (double)xr[i]; rb[i] = v; s1 += v; }
    red[tid] = s1; __syncthreads();
    for (int s = 128; s > 0; s >>= 1) { if (tid < s) red[tid] += red[tid+s]; __syncthreads(); }
    double mu = red[0]/(double)K;
    __syncthreads();
    double s2 = 0.0;
    for (int i = tid; i < K; i += 256) { double d = rb[i]-mu; s2 += d*d; }
    red[tid] = s2; __syncthreads();
    for (int s = 128; s > 0; s >>= 1) { if (tid < s) red[tid] += red[tid+s]; __syncthreads(); }
    double r = 1.0 / sqrt(red[0]/(double)K + (double)eps);
    int bn = row / rows_per_bn;
    float* orow = out + (size_t)row*K;
    for (int i = tid; i < K; i += 256) {
        double y = (rb[i]-mu)*r;
        if (gamma) y = y*(double)gamma[i] + (double)beta[i];
        if (sh)    y = y*(1.0 + (double)sc[(size_t)bn*modstride + i])
                     + (double)sh[(size_t)bn*modstride + i];
        orow[i] = (float)y;
    }
}

// ---------------- HGRN gated scan:  h_t = sig(F)*h + silu(I)*(1-sig(F)) ----
__global__ void k_scan(const float* __restrict__ F, const float* __restrict__ I,
                       float* __restrict__ O, int n_outer, long long outer_stride,
                       int n_inner, long long t_stride, int T)
{
    long long chain = (long long)blockIdx.x*blockDim.x + threadIdx.x;
    if (chain >= (long long)n_outer*n_inner) return;
    long long base = (chain / n_inner)*outer_stride + (chain % n_inner);
    double h = 0.0;
    for (int t = 0; t < T; ++t) {
        long long idx = base + (long long)t*t_stride;
        double fp = (double)F[idx], ip = (double)I[idx];
        double f = 1.0/(1.0+exp(-fp));
        double v = (ip/(1.0+exp(-ip)))*(1.0-f);
        h = f*h + v;
        O[idx] = (float)h;
    }
}

// ---------------- o = rmsnorm(o) * g * sigmoid(g)  (in place, f64) ---------
__global__ void k_ogate(float* __restrict__ O, const float* __restrict__ G, int K)
{
    extern __shared__ double rb[];
    __shared__ double red[256];
    const int row = blockIdx.x, tid = threadIdx.x;
    float* orow = O + (size_t)row*K;
    const float* grow = G + (size_t)row*K;
    double ss = 0.0;
    for (int i = tid; i < K; i += 256) { double v = (double)orow[i]; rb[i] = v; ss += v*v; }
    red[tid] = ss; __syncthreads();
    for (int s = 128; s > 0; s >>= 1) { if (tid < s) red[tid] += red[tid+s]; __syncthreads(); }
    double rms = 1.0 / sqrt(red[0]/(double)K + 1e-8);
    for (int i = tid; i < K; i += 256) {
        double g = (double)grow[i];
        orow[i] = (float)(rb[i]*rms * g / (1.0 + exp(-g)));
    }
}

// ---------------- misc elementwise -----------------------------------------
__global__ void k_add(const float* __restrict__ a, const float* __restrict__ b,
                      float* __restrict__ o, int n)
{
    int i = blockIdx.x*256 + threadIdx.x;
    if (i < n) o[i] = a[i] + b[i];
}

__global__ void k_resid_attn(float* __restrict__ xt, const float* __restrict__ acc,
                             const float* __restrict__ refo, const float* __restrict__ mod)
{
    int idx = blockIdx.x*256 + threadIdx.x;            // 2048*1152 exact
    int r = idx / 1152, d = idx - r*1152;
    int bn = r >> 8, l = r & 255;
    float ga = mod[(size_t)bn*6912 + 2*1152 + d];
    float rv = refo[((size_t)((bn>>2)*256 + l))*1152 + d];
    xt[idx] += ga*(acc[idx] + rv);
}

__global__ void k_resid_mlp(float* __restrict__ xt, const float* __restrict__ t2,
                            const float* __restrict__ mod)
{
    int idx = blockIdx.x*256 + threadIdx.x;
    int r = idx / 1152, d = idx - r*1152;
    int bn = r >> 8;
    xt[idx] += mod[(size_t)bn*6912 + 5*1152 + d] * t2[idx];
}

// xt = patchify(x)@xe_w + xe_b + pos + feats0
__global__ void k_patchify(const float* __restrict__ x, const float* __restrict__ w,
                           const float* __restrict__ bias, const float* __restrict__ pos,
                           const float* __restrict__ f0, float* __restrict__ xt)
{
    int idx = blockIdx.x*256 + threadIdx.x;            // 2048*1152 exact
    int r = idx / 1152, o = idx - r*1152;
    int bn = r >> 8, p = r & 255;
    int y = p >> 4, xx = p & 15;
    float acc = bias[o] + pos[(size_t)p*1152 + o] + f0[idx];
#pragma unroll
    for (int c = 0; c < 4; ++c)
#pragma unroll
        for (int ky = 0; ky < 2; ++ky)
#pragma unroll
            for (int kx = 0; kx < 2; ++kx)
                acc += x[((size_t)(bn*4 + c)*32 + 2*y+ky)*32 + 2*xx+kx]
                     * w[o*16 + c*4 + ky*2 + kx];
    xt[idx] = acc;
}

__global__ void k_unpatch(const float* __restrict__ flo, float* __restrict__ out)
{
    int idx = blockIdx.x*256 + threadIdx.x;            // 65536 exact
    int xx = idx & 31, y = (idx>>5)&31, ch = (idx>>10)&7, b = idx>>13;
    int hp = y>>1, py = y&1, wp = xx>>1, px = xx&1;
    out[idx] = flo[((size_t)(b*256 + hp*16 + wp))*32 + (py*2+px)*8 + ch];
}

// ---------------- generic tiled GEMM: C[M,N] = A[M,K] @ W[N,K]^T -----------
// AMODE: 0 = linear A;  1 = patch-embed gather from x_cond (8,6,512,512),
//        2 = 2x2/s2 down-conv gather from token-major h (8,1024,1152)
//            with permuted k' = (ky*2+kx)*1152 + c so reads are contiguous.
// WMODE: 0 = row-major N x K;  1 = sa_dc_w (o,c,2,2) addressed by permuted k'.
// WQ   : ternary-quantize W on load (f64 decision; {-1,0,1} in LDS, /s in epi).
// GATE : fused hgrn gate -- W has 2N rows; C = silu(A@W[0:N]^T)*(A@W[N:2N]^T).
template<int AMODE>
DEV float4 load_a4(const float* __restrict__ A, int row, int k, int M, int K)
{
    float4 z = {0.f,0.f,0.f,0.f};
    if (row >= M) return z;
    if constexpr (AMODE == 0) {
        return *reinterpret_cast<const float4*>(A + (size_t)row*K + k);
    } else if constexpr (AMODE == 1) {
        int b = row>>10, p = row&1023, oy = p>>5, ox = p&31;
        int c = k>>8, ky = (k>>4)&15, kx = k&15;
        return *reinterpret_cast<const float4*>(
            A + (((size_t)(b*6+c)*512 + (size_t)(oy*16+ky))*512 + (size_t)(ox*16+kx)));
    } else {
        int b = row>>8, y = (row>>4)&15, x = row&15;
        int q = k/1152, c = k - q*1152, ky = q>>1, kx = q&1;
        return *reinterpret_cast<const float4*>(
            A + (size_t)(b*1024 + (2*y+ky)*32 + 2*x+kx)*1152 + c);
    }
}

template<int WMODE>
DEV void load_w4(const float* __restrict__ W, int row, int k, int Nbound, int K, float o[4])
{
    if (row >= Nbound) { o[0]=o[1]=o[2]=o[3]=0.f; return; }
    if constexpr (WMODE == 0) {
        float4 v = *reinterpret_cast<const float4*>(W + (size_t)row*K + k);
        o[0]=v.x; o[1]=v.y; o[2]=v.z; o[3]=v.w;
    } else {
        int q = k/1152, c = k - q*1152;
        const float* p = W + (size_t)row*4608 + (size_t)c*4 + q;
        o[0]=p[0]; o[1]=p[4]; o[2]=p[8]; o[3]=p[12];
    }
}

template<int AMODE, int WMODE, int WQ, int GATE>
__global__ __launch_bounds__(256)
void k_gemm(const float* __restrict__ A, const float* __restrict__ W,
            const double* __restrict__ wsum, long long wcount,
            const float* __restrict__ bias, float* __restrict__ C,
            int M, int N, int K, int accum)
{
    __shared__ float As[16][64];
    __shared__ float Ws[16][64];
    __shared__ float Ws2[GATE?16:1][GATE?64:1];
    const int tid = threadIdx.x;
    const int tx = tid & 15, ty = tid >> 4;
    const int m0 = blockIdx.y*64, n0 = blockIdx.x*64;
    const int lr = tid >> 2;            // tile row 0..63
    const int lc = (tid & 3) * 4;       // tile k-col {0,4,8,12}

    double sd = 1.0;
    if constexpr (WQ) {
        sd = 1.0 / fmax(*wsum / (double)wcount, 1e-5);   // wq = clip(rint(w*sd),-1,1)/sd
    }

    float acc[4][4] = {};
    float acc2[GATE?4:1][GATE?4:1] = {};

    for (int kt = 0; kt < K; kt += 16) {
        {
            float4 v = load_a4<AMODE>(A, m0+lr, kt+lc, M, K);
            As[lc+0][lr]=v.x; As[lc+1][lr]=v.y; As[lc+2][lr]=v.z; As[lc+3][lr]=v.w;
        }
        {
            float wv[4];
            load_w4<WMODE>(W, n0+lr, kt+lc, N, K, wv);
            if constexpr (WQ)
                for (int i = 0; i < 4; ++i)
                    wv[i] = (float)fmin(fmax(rint((double)wv[i]*sd), -1.0), 1.0);
            Ws[lc+0][lr]=wv[0]; Ws[lc+1][lr]=wv[1]; Ws[lc+2][lr]=wv[2]; Ws[lc+3][lr]=wv[3];
            if constexpr (GATE) {
                float w2[4];
                load_w4<WMODE>(W, n0+lr+N, kt+lc, 2*N, K, w2);
                for (int i = 0; i < 4; ++i)
                    w2[i] = (float)fmin(fmax(rint((double)w2[i]*sd), -1.0), 1.0);
                Ws2[lc+0][lr]=w2[0]; Ws2[lc+1][lr]=w2[1]; Ws2[lc+2][lr]=w2[2]; Ws2[lc+3][lr]=w2[3];
            }
        }
        __syncthreads();
#pragma unroll
        for (int k = 0; k < 16; ++k) {
            float4 av = *reinterpret_cast<const float4*>(&As[k][ty*4]);
            float4 bv = *reinterpret_cast<const float4*>(&Ws[k][tx*4]);
            float a[4] = {av.x,av.y,av.z,av.w};
            float b[4] = {bv.x,bv.y,bv.z,bv.w};
#pragma unroll
            for (int i = 0; i < 4; ++i)
#pragma unroll
                for (int j = 0; j < 4; ++j) acc[i][j] += a[i]*b[j];
            if constexpr (GATE) {
                float4 cv = *reinterpret_cast<const float4*>(&Ws2[k][tx*4]);
                float b2[4] = {cv.x,cv.y,cv.z,cv.w};
#pragma unroll
                for (int i = 0; i < 4; ++i)
#pragma unroll
                    for (int j = 0; j < 4; ++j) acc2[i][j] += a[i]*b2[j];
            }
        }
        __syncthreads();
    }

#pragma unroll
    for (int i = 0; i < 4; ++i) {
        int row = m0 + ty*4 + i;
        if (row >= M) continue;
#pragma unroll
        for (int j = 0; j < 4; ++j) {
            int col = n0 + tx*4 + j;
            if (col >= N) continue;
            float v;
            if constexpr (GATE) {
                double g = (double)acc[i][j]/sd, y = (double)acc2[i][j]/sd;
                v = (float)(g/(1.0+exp(-g)) * y);      // silu(g)*y in f64
            } else {
                if constexpr (WQ) v = (float)((double)acc[i][j]/sd);
                else              v = acc[i][j];
                if (bias) v += bias[col];
            }
            size_t o = (size_t)row*N + col;
            C[o] = accum ? C[o] + v : v;
        }
    }
}

// ---------------------------------------------------------------------------
extern "C" void kernel_launch(void* const* d_in, const int* in_sizes, int n_in,
                              void* d_out, int out_size, void* d_ws, size_t ws_size,
                              hipStream_t stream)
{
    (void)in_sizes; (void)n_in; (void)out_size;
    auto in = [&](int i){ return (const float*)d_in[i]; };

    const float *X = in(0), *T = in(1), *Y = in(2), *XC = in(3), *REF = in(4);
    const float *xe_w = in(6), *xe_b = in(7), *pos = in(8);
    const float *te_w1 = in(9), *te_b1 = in(10), *te_w2 = in(11), *te_b2 = in(12);
    const float *pp_w = in(13), *pp_b = in(14);
    const float *sa_pe_w = in(15), *sa_pe_b = in(16);
    const float *sa_ln_g = in(17), *sa_ln_b = in(18);
    const float *sa_gate_w = in(19), *sa_down_w = in(20);
    const float *sa_dc_w = in(21), *sa_dc_b = in(22);
    const float *ada_w = in(23), *ada_b = in(24);
    const float *sa_wi = in(25), *sa_wf = in(26), *sa_wg = in(27), *sa_wo = in(28);
    const float *mv_wi = in(29), *mv_wf = in(30), *mv_wg = in(31), *mv_wo = in(32);
    const float *rf_wi = in(33), *rf_wf = in(34), *rf_wg = in(35), *rf_wo = in(36);
    const float *gate_w = in(37), *down_w = in(38);
    const float *fl_w = in(39), *fl_b = in(40), *fl_ada_w = in(41), *fl_ada_b = in(42);
    float* OUT = (float*)d_out;

    // ---------- workspace layout ----------
    size_t off = 0;
    auto AL = [&](size_t bytes){ off = (off+255)&~(size_t)255; size_t r = off; off += bytes; return r; };
    const size_t oScale = AL(37*8);
    const size_t oPart  = AL(512*8);
    const size_t oSM1 = AL(8*1152*4), oSM2 = AL(8*1152*4), oSM3 = AL(8*1152*4);
    const size_t oCB  = AL(8*1152*4), oQC  = AL(8*1152*4);
    const size_t oMOD = AL(8*6912*4);
    const size_t oH   = AL((size_t)8192*1152*4);
    const size_t oT1  = AL((size_t)2048*1152*4);
    const size_t oINT = AL((size_t)2048*4608*4);
    const size_t oF0  = AL((size_t)2048*1152*4);
    const size_t oXT  = AL((size_t)2048*1152*4);
    const size_t oXM  = AL((size_t)2048*1152*4);
    const size_t oQX  = AL((size_t)2048*1152*4);
    const size_t oFB  = AL((size_t)2048*1152*4);
    const size_t oIB  = AL((size_t)2048*1152*4);
    const size_t oGB  = AL((size_t)2048*1152*4);
    const size_t oOB  = AL((size_t)2048*1152*4);
    const size_t oACC = AL((size_t)2048*1152*4);
    const size_t oRQ  = AL((size_t)512*1152*4);
    const size_t oRO  = AL((size_t)512*1152*4);
    if (off > ws_size) return;   // fail loudly (output stays wrong) instead of corrupting

    char* w8 = (char*)d_ws;
    double* scales = (double*)(w8 + oScale);
    double* parts  = (double*)(w8 + oPart);
    float *SM1=(float*)(w8+oSM1), *SM2=(float*)(w8+oSM2), *SM3=(float*)(w8+oSM3);
    float *CB=(float*)(w8+oCB), *QC=(float*)(w8+oQC), *MOD=(float*)(w8+oMOD);
    float *H=(float*)(w8+oH), *T1=(float*)(w8+oT1), *INT=(float*)(w8+oINT);
    float *F0=(float*)(w8+oF0), *XT=(float*)(w8+oXT), *XM=(float*)(w8+oXM);
    float *QX=(float*)(w8+oQX), *FB=(float*)(w8+oFB), *IB=(float*)(w8+oIB);
    float *GB=(float*)(w8+oGB), *OB=(float*)(w8+oOB), *ACC=(float*)(w8+oACC);
    float *RQ=(float*)(w8+oRQ), *RO=(float*)(w8+oRO);

    // ---------- weight scales (deterministic) ----------
    hipMemsetAsync(w8 + oScale, 0, 37*8, stream);
    struct WE { const float* w; long long n; int slot; };
    WE wl[37]; int nw = 0;
    auto addw = [&](const float* w, long long n, int s){ wl[nw].w=w; wl[nw].n=n; wl[nw].slot=s; nw++; };
    addw(te_w1, 294912, 0); addw(te_w2, 1327104, 1); addw(pp_w, 884736, 2);
    addw(sa_gate_w, 10616832, 3); addw(sa_down_w, 5308416, 4);
    for (int l = 0; l < 2; ++l) {
        int sb = 5 + l*15;
        addw(ada_w + (size_t)l*7962624, 7962624, sb+0);
        addw(sa_wi + (size_t)l*1327104, 1327104, sb+1);
        addw(sa_wf + (size_t)l*1327104, 1327104, sb+2);
        addw(sa_wg + (size_t)l*1327104, 1327104, sb+3);
        addw(sa_wo + (size_t)l*1327104, 1327104, sb+4);
        addw(mv_wi + (size_t)l*1327104, 1327104, sb+5);
        addw(mv_wf + (size_t)l*1327104, 1327104, sb+6);
        addw(mv_wg + (size_t)l*1327104, 1327104, sb+7);
        addw(mv_wo + (size_t)l*1327104, 1327104, sb+8);
        addw(rf_wi + (size_t)l*1327104, 1327104, sb+9);
        addw(rf_wf + (size_t)l*1327104, 1327104, sb+10);
        addw(rf_wg + (size_t)l*1327104, 1327104, sb+11);
        addw(rf_wo + (size_t)l*1327104, 1327104, sb+12);
        addw(gate_w + (size_t)l*10616832, 10616832, sb+13);
        addw(down_w + (size_t)l*5308416, 5308416, sb+14);
    }
    addw(fl_ada_w, 2654208, 35); addw(fl_w, 36864, 36);
    for (int i = 0; i < nw; ++i) {
        k_abssum_part<<<512, 256, 0, stream>>>(wl[i].w, wl[i].n, parts);
        k_abssum_fin<<<1, 512, 0, stream>>>(parts, scales + wl[i].slot);
    }

    // ---------- launch helpers ----------
    auto gemmQ = [&](const float* Ain, const float* Win, int slot, long long wc,
                     const float* b, float* Cout, int M, int N, int K, int accum){
        dim3 g((unsigned)((N+63)/64), (unsigned)((M+63)/64));
        k_gemm<0,0,1,0><<<g, 256, 0, stream>>>(Ain, Win, scales+slot, wc, b, Cout, M, N, K, accum);
    };
    auto gemmGate = [&](const float* Ain, const float* Win, int slot, long long wc,
                        float* Cout, int M){
        dim3 g(72u, (unsigned)((M+63)/64));
        k_gemm<0,0,1,1><<<g, 256, 0, stream>>>(Ain, Win, scales+slot, wc, nullptr, Cout, M, 4608, 1152, 0);
    };
    auto rsq = [&](const float* xi, float* xo, int M, int K, int silu){
        k_rsq<<<M, 256, (size_t)K*8, stream>>>(xi, xo, K, silu);
    };
    auto lnmod = [&](const float* xi, float* xo, int M, const float* g, const float* b,
                     const float* sh, const float* sc, int mstride, float eps){
        k_ln<<<M, 256, 1152*8, stream>>>(xi, xo, 1152, g, b, sh, sc, mstride, 256, eps);
    };

    // ---------- conditioning vector c ----------
    k_temb<<<8, 128, 0, stream>>>(T, SM1);                       // (8,256)
    rsq(SM1, SM2, 8, 256, 0);
    gemmQ(SM2, te_w1, 0, 294912, te_b1, SM3, 8, 1152, 256, 0);
    rsq(SM3, SM1, 8, 1152, 1);                                   // silu then rmsnorm+quant
    gemmQ(SM1, te_w2, 1, 1327104, te_b2, SM2, 8, 1152, 1152, 0);
    rsq(Y, SM1, 8, 768, 0);
    gemmQ(SM1, pp_w, 2, 884736, pp_b, SM3, 8, 1152, 768, 0);
    k_add<<<36, 256, 0, stream>>>(SM2, SM3, CB, 9216);           // c
    rsq(CB, QC, 8, 1152, 1);                                     // quant(silu(c)) shared

    // ---------- spatial adapter: patch embed + block 0 only ----------
    k_gemm<1,0,0,0><<<dim3(18,128), 256, 0, stream>>>(XC, sa_pe_w, scales, 1,
                                                      sa_pe_b, H, 8192, 1152, 1536, 0);
    for (int ch = 0; ch < 4; ++ch) {                             // chunk 2048 tokens
        float* Hrow = H + (size_t)ch*2048*1152;
        k_ln<<<2048, 256, 1152*8, stream>>>(Hrow, T1, 1152, sa_ln_g, sa_ln_b,
                                            nullptr, nullptr, 0, 256, 1e-5f);
        rsq(T1, T1, 2048, 1152, 0);
        gemmGate(T1, sa_gate_w, 3, 10616832, INT, 2048);
        rsq(INT, INT, 2048, 4608, 0);
        gemmQ(INT, sa_down_w, 4, 5308416, nullptr, Hrow, 2048, 1152, 4608, 0);
    }
    k_gemm<2,1,0,0><<<dim3(18,32), 256, 0, stream>>>(H, sa_dc_w, scales, 1,
                                                     sa_dc_b, F0, 2048, 1152, 4608, 0);

    // ---------- patchify latents + pos + feats0 ----------
    k_patchify<<<9216, 256, 0, stream>>>(X, xe_w, xe_b, pos, F0, XT);
    rsq(REF, RQ, 512, 1152, 0);                                  // ref quant (2 unique batches)

    // ---------- transformer blocks ----------
    for (int l = 0; l < 2; ++l) {
        int sb = 5 + l*15;
        const float *wada = ada_w + (size_t)l*7962624, *bada = ada_b + (size_t)l*6912;
        const float *swi = sa_wi + (size_t)l*1327104, *swf = sa_wf + (size_t)l*1327104;
        const float *swg = sa_wg + (size_t)l*1327104, *swo = sa_wo + (size_t)l*1327104;
        const float *mwi = mv_wi + (size_t)l*1327104, *mwf = mv_wf + (size_t)l*1327104;
        const float *mwg = mv_wg + (size_t)l*1327104, *mwo = mv_wo + (size_t)l*1327104;
        const float *rwi = rf_wi + (size_t)l*1327104, *rwf = rf_wf + (size_t)l*1327104;
        const float *rwg = rf_wg + (size_t)l*1327104, *rwo = rf_wo + (size_t)l*1327104;
        const float *wgt = gate_w + (size_t)l*10616832, *wdn = down_w + (size_t)l*5308416;

        gemmQ(QC, wada, sb+0, 7962624, bada, MOD, 8, 6912, 1152, 0);

        lnmod(XT, XM, 2048, nullptr, nullptr, MOD+0, MOD+1152, 6912, 1e-6f);
        rsq(XM, QX, 2048, 1152, 0);

        // self attention (seq = 256 tokens)
        gemmQ(QX, swf, sb+2, 1327104, nullptr, FB, 2048, 1152, 1152, 0);
        gemmQ(QX, swi, sb+1, 1327104, nullptr, IB, 2048, 1152, 1152, 0);
        gemmQ(QX, swg, sb+3, 1327104, nullptr, GB, 2048, 1152, 1152, 0);
        k_scan<<<36, 256, 0, stream>>>(FB, IB, OB, 8, 294912LL, 1152, 1152LL, 256);
        k_ogate<<<2048, 256, 1152*8, stream>>>(OB, GB, 1152);
        rsq(OB, OB, 2048, 1152, 0);
        gemmQ(OB, swo, sb+4, 1327104, nullptr, ACC, 2048, 1152, 1152, 0);

        // multi-view attention (seq = 4 views; token layout unchanged)
        gemmQ(QX, mwf, sb+6, 1327104, nullptr, FB, 2048, 1152, 1152, 0);
        gemmQ(QX, mwi, sb+5, 1327104, nullptr, IB, 2048, 1152, 1152, 0);
        gemmQ(QX, mwg, sb+7, 1327104, nullptr, GB, 2048, 1152, 1152, 0);
        k_scan<<<2304, 256, 0, stream>>>(FB, IB, OB, 2, 1179648LL, 294912, 294912LL, 4);
        k_ogate<<<2048, 256, 1152*8, stream>>>(OB, GB, 1152);
        rsq(OB, OB, 2048, 1152, 0);
        gemmQ(OB, mwo, sb+8, 1327104, nullptr, ACC, 2048, 1152, 1152, 1);   // +=

        // ref attention on 2 unique batches
        gemmQ(RQ, rwf, sb+10, 1327104, nullptr, FB, 512, 1152, 1152, 0);
        gemmQ(RQ, rwi, sb+9,  1327104, nullptr, IB, 512, 1152, 1152, 0);
        gemmQ(RQ, rwg, sb+11, 1327104, nullptr, GB, 512, 1152, 1152, 0);
        k_scan<<<9, 256, 0, stream>>>(FB, IB, OB, 2, 294912LL, 1152, 1152LL, 256);
        k_ogate<<<512, 256, 1152*8, stream>>>(OB, GB, 1152);
        rsq(OB, OB, 512, 1152, 0);
        gemmQ(OB, rwo, sb+12, 1327104, nullptr, RO, 512, 1152, 1152, 0);

        k_resid_attn<<<9216, 256, 0, stream>>>(XT, ACC, RO, MOD);

        // MLP
        lnmod(XT, XM, 2048, nullptr, nullptr, MOD+3*1152, MOD+4*1152, 6912, 1e-6f);
        rsq(XM, QX, 2048, 1152, 0);
        gemmGate(QX, wgt, sb+13, 10616832, INT, 2048);
        rsq(INT, INT, 2048, 4608, 0);
        gemmQ(INT, wdn, sb+14, 5308416, nullptr, OB, 2048, 1152, 4608, 0);
        k_resid_mlp<<<9216, 256, 0, stream>>>(XT, OB, MOD);
    }

    // ---------- final layer + unpatchify ----------
    gemmQ(QC, fl_ada_w, 35, 2654208, fl_ada_b, MOD, 8, 2304, 1152, 0);
    lnmod(XT, XM, 2048, nullptr, nullptr, MOD+0, MOD+1152, 2304, 1e-6f);
    rsq(XM, QX, 2048, 1152, 0);
    gemmQ(QX, fl_w, 36, 36864, fl_b, FB, 2048, 32, 1152, 0);
    k_unpatch<<<256, 256, 0, stream>>>(FB, OUT);
}

// Round 4
// 8768.247 us; speedup vs baseline: 1.4187x; 1.4187x over previous
//
#include <hip/hip_runtime.h>

#define DEV __device__ __forceinline__

typedef __attribute__((ext_vector_type(4))) int i32x4;

// ---------------------------------------------------------------------------
// TernaryMVAdapter forward on MI355X. Round 3: f64-exact pipeline.
//  * every non-integer intermediate stored/computed in f64 (matches np-f64
//    reference to ~1e-15, so int8/ternary rounding decisions never flip)
//  * bitlinear GEMMs: exact int8 x ternary via mfma_i32_16x16x64_i8
//  * plain convs (patch-embed, down-conv, patchify): f64 SIMT GEMM
// Structural simplifications (output-equivalent):
//  * SA blocks 1,2 dead (only feats[0] consumed) -> skipped
//  * ref_rep rows repeat 4x -> ref attention on 2 unique batches
//  * mv attention = permutation of tokens -> only the scan walks view order
// ---------------------------------------------------------------------------

// ---------------- fused deterministic |w| sums (37 slots) ------------------
struct WList { const float* p[37]; long long n[37]; };

__global__ void k_abssum_all(WList wl, double* __restrict__ partials)
{
    const int slot = blockIdx.y;
    const float* w = wl.p[slot];
    const long long n = wl.n[slot];
    __shared__ double sm[256];
    double s = 0.0;
    for (long long i = (long long)blockIdx.x*256 + threadIdx.x; i < n; i += 32LL*256)
        s += (double)fabsf(w[i]);
    sm[threadIdx.x] = s;
    __syncthreads();
    for (int k = 128; k > 0; k >>= 1) {
        if ((int)threadIdx.x < k) sm[threadIdx.x] += sm[threadIdx.x + k];
        __syncthreads();
    }
    if (threadIdx.x == 0) partials[slot*32 + blockIdx.x] = sm[0];
}

__global__ void k_abssum_fin(const double* __restrict__ partials, double* __restrict__ out)
{
    const int slot = blockIdx.x;
    if (threadIdx.x == 0) {
        double s = 0.0;
        for (int i = 0; i < 32; ++i) s += partials[slot*32 + i];
        out[slot] = s;
    }
}

// ---------------- timestep frequency embedding (f64) -----------------------
__global__ void k_temb(const float* __restrict__ t, double* __restrict__ out)
{
    int b = blockIdx.x, j = threadIdx.x;               // 8 x 128
    double fr  = exp(-9.210340371976184 * (double)j / 128.0);
    double ang = (double)t[b] * fr;
    out[b*256 + j]       = cos(ang);
    out[b*256 + 128 + j] = sin(ang);
}

// ---------------- rmsnorm + int8 absmax quant (f64) ------------------------
template<typename TI>
__global__ void k_rsq8(const TI* __restrict__ x, signed char* __restrict__ q8,
                       double* __restrict__ dscale, int K, int pre_silu)
{
    extern __shared__ double rb[];
    __shared__ double red[256], red2[256];
    const int row = blockIdx.x, tid = threadIdx.x;
    const TI* xr = x + (size_t)row*K;
    double ss = 0.0, am = 0.0;
    for (int i = tid; i < K; i += 256) {
        double v = (double)xr[i];
        if (pre_silu) v = v / (1.0 + exp(-v));
        rb[i] = v; ss += v*v; am = fmax(am, fabs(v));
    }
    red[tid] = ss; red2[tid] = am;
    __syncthreads();
    for (int s = 128; s > 0; s >>= 1) {
        if (tid < s) { red[tid] += red[tid+s]; red2[tid] = fmax(red2[tid], red2[tid+s]); }
        __syncthreads();
    }
    double rms = 1.0 / sqrt(red[0]/(double)K + 1e-8);
    double s   = 127.0 / fmax(red2[0]*rms, 1e-5);
    signed char* orow = q8 + (size_t)row*K;
    for (int i = tid; i < K; i += 256)
        orow[i] = (signed char)(int)fmin(fmax(rint(rb[i]*rms*s), -128.0), 127.0);
    if (tid == 0) dscale[row] = s;
}

// ---------------- layernorm(+gb/+mod) + rmsnorm + int8 quant (f64) ---------
__global__ void k_lnq8(const double* __restrict__ x, signed char* __restrict__ q8,
                       double* __restrict__ dscale, int K,
                       const float* __restrict__ gamma, const float* __restrict__ beta,
                       const double* __restrict__ sh, const double* __restrict__ sc,
                       int modstride, double eps)
{
    extern __shared__ double rb[];
    __shared__ double red[256], red2[256];
    const int row = blockIdx.x, tid = threadIdx.x;
    const double* xr = x + (size_t)row*K;
    double s1 = 0.0;
    for (int i = tid; i < K; i += 256) { double v = xr[i]; rb[i] = v; s1 += v; }
    red[tid] = s1; __syncthreads();
    for (int s = 128; s > 0; s >>= 1) { if (tid < s) red[tid] += red[tid+s]; __syncthreads(); }
    double mu = red[0]/(double)K;
    __syncthreads();
    double s2 = 0.0;
    for (int i = tid; i < K; i += 256) { double d = rb[i]-mu; s2 += d*d; }
    red[tid] = s2; __syncthreads();
    for (int s = 128; s > 0; s >>= 1) { if (tid < s) red[tid] += red[tid+s]; __syncthreads(); }
    double r = 1.0 / sqrt(red[0]/(double)K + eps);
    const int bn = row >> 8;
    __syncthreads();
    double ss = 0.0, am = 0.0;
    for (int i = tid; i < K; i += 256) {
        double y = (rb[i]-mu)*r;
        if (gamma) y = y*(double)gamma[i] + (double)beta[i];
        if (sh)    y = y*(1.0 + sc[(size_t)bn*modstride + i]) + sh[(size_t)bn*modstride + i];
        rb[i] = y; ss += y*y; am = fmax(am, fabs(y));
    }
    red[tid] = ss; red2[tid] = am;
    __syncthreads();
    for (int s = 128; s > 0; s >>= 1) {
        if (tid < s) { red[tid] += red[tid+s]; red2[tid] = fmax(red2[tid], red2[tid+s]); }
        __syncthreads();
    }
    double rms = 1.0 / sqrt(red[0]/(double)K + 1e-8);
    double s   = 127.0 / fmax(red2[0]*rms, 1e-5);
    signed char* orow = q8 + (size_t)row*K;
    for (int i = tid; i < K; i += 256)
        orow[i] = (signed char)(int)fmin(fmax(rint(rb[i]*rms*s), -128.0), 127.0);
    if (tid == 0) dscale[row] = s;
}

// ---------------- ogate (rmsnorm*g*sig(g)) + rmsnorm + quant (f64) ---------
__global__ void k_ogateq8(const double* __restrict__ O, const double* __restrict__ G,
                          signed char* __restrict__ q8, double* __restrict__ dscale, int K)
{
    extern __shared__ double rb[];
    __shared__ double red[256], red2[256];
    const int row = blockIdx.x, tid = threadIdx.x;
    const double* orow = O + (size_t)row*K;
    const double* grow = G + (size_t)row*K;
    double ss = 0.0;
    for (int i = tid; i < K; i += 256) { double v = orow[i]; rb[i] = v; ss += v*v; }
    red[tid] = ss; __syncthreads();
    for (int s = 128; s > 0; s >>= 1) { if (tid < s) red[tid] += red[tid+s]; __syncthreads(); }
    double rmso = 1.0 / sqrt(red[0]/(double)K + 1e-8);
    __syncthreads();
    double ss2 = 0.0, am = 0.0;
    for (int i = tid; i < K; i += 256) {
        double g = grow[i];
        double y = rb[i]*rmso * g / (1.0 + exp(-g));
        rb[i] = y; ss2 += y*y; am = fmax(am, fabs(y));
    }
    red[tid] = ss2; red2[tid] = am;
    __syncthreads();
    for (int s = 128; s > 0; s >>= 1) {
        if (tid < s) { red[tid] += red[tid+s]; red2[tid] = fmax(red2[tid], red2[tid+s]); }
        __syncthreads();
    }
    double rms = 1.0 / sqrt(red[0]/(double)K + 1e-8);
    double s   = 127.0 / fmax(red2[0]*rms, 1e-5);
    signed char* qrow = q8 + (size_t)row*K;
    for (int i = tid; i < K; i += 256)
        qrow[i] = (signed char)(int)fmin(fmax(rint(rb[i]*rms*s), -128.0), 127.0);
    if (tid == 0) dscale[row] = s;
}

// ---------------- HGRN gated scan (f64, O may alias I) ---------------------
__global__ void k_scan(const double* F, const double* I, double* O,
                       int n_outer, long long outer_stride,
                       int n_inner, long long t_stride, int T)
{
    long long chain = (long long)blockIdx.x*blockDim.x + threadIdx.x;
    if (chain >= (long long)n_outer*n_inner) return;
    long long base = (chain / n_inner)*outer_stride + (chain % n_inner);
    double h = 0.0;
    for (int t = 0; t < T; ++t) {
        long long idx = base + (long long)t*t_stride;
        double fp = F[idx], ip = I[idx];
        double f = 1.0/(1.0+exp(-fp));
        double v = (ip/(1.0+exp(-ip)))*(1.0-f);
        h = f*h + v;
        O[idx] = h;
    }
}

// ---------------- misc elementwise (f64) -----------------------------------
__global__ void k_add(const double* __restrict__ a, const double* __restrict__ b,
                      double* __restrict__ o, int n)
{
    int i = blockIdx.x*256 + threadIdx.x;
    if (i < n) o[i] = a[i] + b[i];
}

__global__ void k_resid_attn(double* __restrict__ xt, const double* __restrict__ acc,
                             const double* __restrict__ refo, const double* __restrict__ mod)
{
    int idx = blockIdx.x*256 + threadIdx.x;            // 2048*1152 exact
    int r = idx / 1152, d = idx - r*1152;
    int bn = r >> 8, l = r & 255;
    double ga = mod[(size_t)bn*6912 + 2*1152 + d];
    double rv = refo[((size_t)((bn>>2)*256 + l))*1152 + d];
    xt[idx] += ga*(acc[idx] + rv);
}

__global__ void k_resid_mlp(double* __restrict__ xt, const double* __restrict__ t2,
                            const double* __restrict__ mod)
{
    int idx = blockIdx.x*256 + threadIdx.x;
    int r = idx / 1152, d = idx - r*1152;
    int bn = r >> 8;
    xt[idx] += mod[(size_t)bn*6912 + 5*1152 + d] * t2[idx];
}

// xt = patchify(x)@xe_w + xe_b + pos + feats0   (f64)
__global__ void k_patchify(const float* __restrict__ x, const float* __restrict__ w,
                           const float* __restrict__ bias, const float* __restrict__ pos,
                           const double* __restrict__ f0, double* __restrict__ xt)
{
    int idx = blockIdx.x*256 + threadIdx.x;            // 2048*1152 exact
    int r = idx / 1152, o = idx - r*1152;
    int bn = r >> 8, p = r & 255;
    int y = p >> 4, xx = p & 15;
    double acc = (double)bias[o] + (double)pos[(size_t)p*1152 + o] + f0[idx];
#pragma unroll
    for (int c = 0; c < 4; ++c)
#pragma unroll
        for (int ky = 0; ky < 2; ++ky)
#pragma unroll
            for (int kx = 0; kx < 2; ++kx)
                acc += (double)x[((size_t)(bn*4 + c)*32 + 2*y+ky)*32 + 2*xx+kx]
                     * (double)w[o*16 + c*4 + ky*2 + kx];
    xt[idx] = acc;
}

__global__ void k_unpatch(const double* __restrict__ flo, float* __restrict__ out)
{
    int idx = blockIdx.x*256 + threadIdx.x;            // 65536 exact
    int xx = idx & 31, y = (idx>>5)&31, ch = (idx>>10)&7, b = idx>>13;
    int hp = y>>1, py = y&1, wp = xx>>1, px = xx&1;
    out[idx] = (float)flo[((size_t)(b*256 + hp*16 + wp))*32 + (py*2+px)*8 + ch];
}

// ---------------- f64 SIMT GEMM for the two plain convs --------------------
// AMODE 1: patch-embed gather from x_cond (8,6,512,512), k = c*256+ky*16+kx
// AMODE 2: down-conv gather from token-major f64 H (8,1024,1152), permuted
//          k' = (ky*2+kx)*1152 + c
// WMODE 0: row-major N x K f32;  WMODE 1: sa_dc_w (o,c,2,2) by permuted k'
template<int AMODE>
DEV void load_a4d(const void* __restrict__ A, int row, int k, int M, double o[4])
{
    if (row >= M) { o[0]=o[1]=o[2]=o[3]=0.0; return; }
    if constexpr (AMODE == 1) {
        const float* Af = (const float*)A;
        int b = row>>10, p = row&1023, oy = p>>5, ox = p&31;
        int c = k>>8, ky = (k>>4)&15, kx = k&15;
        float4 v = *reinterpret_cast<const float4*>(
            Af + (((size_t)(b*6+c)*512 + (size_t)(oy*16+ky))*512 + (size_t)(ox*16+kx)));
        o[0]=v.x; o[1]=v.y; o[2]=v.z; o[3]=v.w;
    } else {
        const double* Ad = (const double*)A;
        int b = row>>8, y = (row>>4)&15, x = row&15;
        int q = k/1152, c = k - q*1152, ky = q>>1, kx = q&1;
        const double* p = Ad + (size_t)(b*1024 + (2*y+ky)*32 + 2*x+kx)*1152 + c;
        o[0]=p[0]; o[1]=p[1]; o[2]=p[2]; o[3]=p[3];
    }
}

template<int WMODE>
DEV void load_w4d(const float* __restrict__ W, int row, int k, int Nb, int K, double o[4])
{
    if (row >= Nb) { o[0]=o[1]=o[2]=o[3]=0.0; return; }
    if constexpr (WMODE == 0) {
        float4 v = *reinterpret_cast<const float4*>(W + (size_t)row*K + k);
        o[0]=v.x; o[1]=v.y; o[2]=v.z; o[3]=v.w;
    } else {
        int q = k/1152, c = k - q*1152;
        const float* p = W + (size_t)row*4608 + (size_t)c*4 + q;
        o[0]=p[0]; o[1]=p[4]; o[2]=p[8]; o[3]=p[12];
    }
}

template<int AMODE, int WMODE>
__global__ __launch_bounds__(256)
void k_dgemm(const void* __restrict__ A, const float* __restrict__ W,
             const float* __restrict__ bias, double* __restrict__ C,
             int M, int N, int K)
{
    __shared__ double As[16][64];
    __shared__ double Ws[16][64];
    const int tid = threadIdx.x;
    const int tx = tid & 15, ty = tid >> 4;
    const int m0 = blockIdx.y*64, n0 = blockIdx.x*64;
    const int lr = tid >> 2;
    const int lc = (tid & 3) * 4;

    double acc[4][4] = {};

    for (int kt = 0; kt < K; kt += 16) {
        {
            double v[4];
            load_a4d<AMODE>(A, m0+lr, kt+lc, M, v);
            As[lc+0][lr]=v[0]; As[lc+1][lr]=v[1]; As[lc+2][lr]=v[2]; As[lc+3][lr]=v[3];
        }
        {
            double wv[4];
            load_w4d<WMODE>(W, n0+lr, kt+lc, N, K, wv);
            Ws[lc+0][lr]=wv[0]; Ws[lc+1][lr]=wv[1]; Ws[lc+2][lr]=wv[2]; Ws[lc+3][lr]=wv[3];
        }
        __syncthreads();
#pragma unroll
        for (int k = 0; k < 16; ++k) {
            double a[4], b[4];
#pragma unroll
            for (int e = 0; e < 4; ++e) { a[e] = As[k][ty*4+e]; b[e] = Ws[k][tx*4+e]; }
#pragma unroll
            for (int i = 0; i < 4; ++i)
#pragma unroll
                for (int j = 0; j < 4; ++j) acc[i][j] += a[i]*b[j];
        }
        __syncthreads();
    }

#pragma unroll
    for (int i = 0; i < 4; ++i) {
        int row = m0 + ty*4 + i;
        if (row >= M) continue;
#pragma unroll
        for (int j = 0; j < 4; ++j) {
            int col = n0 + tx*4 + j;
            if (col >= N) continue;
            C[(size_t)row*N + col] = acc[i][j] + (bias ? (double)bias[col] : 0.0);
        }
    }
}

// ---------------- int8 MFMA GEMM (exact), f64 dequant ----------------------
template<int GATE>
__global__ __launch_bounds__(256)
void k_qgemm(const signed char* __restrict__ A8, const double* __restrict__ ascale,
             const float* __restrict__ W, const double* __restrict__ wsum, long long wcount,
             const float* __restrict__ bias, double* __restrict__ C,
             int M, int N, int K, int accum)
{
    __shared__ __align__(16) signed char Als[4][128][16];
    __shared__ __align__(16) signed char Bls[4][128][16];
    __shared__ __align__(16) signed char B2ls[GATE?4:1][GATE?128:1][16];
    const int tid = threadIdx.x;
    const int lane = tid & 63, wid = tid >> 6;
    const int wr = wid >> 1, wc = wid & 1;             // 2x2 waves, 64x64 each
    const int m0 = blockIdx.x*128, n0 = blockIdx.y*128;
    const int ks = lane >> 4, fr = lane & 15;

    const double dqw = fmax(*wsum / (double)wcount, 1e-5);  // mean|w|
    const double thr = 0.5 * dqw;                           // ternary threshold

    i32x4 acc[4][4];
    i32x4 acc2[GATE?4:1][4];
#pragma unroll
    for (int i = 0; i < 4; ++i)
#pragma unroll
        for (int j = 0; j < 4; ++j) {
            acc[i][j] = i32x4{0,0,0,0};
            if constexpr (GATE) acc2[i][j] = i32x4{0,0,0,0};
        }

    for (int kt = 0; kt < K; kt += 64) {
#pragma unroll
        for (int c = 0; c < 2; ++c) {
            int idx = tid + c*256;
            int row = idx & 127, kslot = idx >> 7;
            i32x4 v = {0,0,0,0};
            if (m0 + row < M)
                v = *reinterpret_cast<const i32x4*>(A8 + (size_t)(m0+row)*K + kt + kslot*16);
            *reinterpret_cast<i32x4*>(&Als[kslot][row][0]) = v;
        }
#pragma unroll
        for (int c = 0; c < 2; ++c) {
            int idx = tid + c*256;
            int row = idx & 127, kslot = idx >> 7;
            i32x4 pv = {0,0,0,0};
            if (n0 + row < N) {
                const float* wp = W + (size_t)(n0+row)*K + kt + kslot*16;
#pragma unroll
                for (int d = 0; d < 4; ++d) {
                    float4 wv = *reinterpret_cast<const float4*>(wp + d*4);
                    float we[4] = {wv.x, wv.y, wv.z, wv.w};
                    unsigned p = 0;
#pragma unroll
                    for (int e = 0; e < 4; ++e) {
                        double wd = (double)we[e];
                        int q = (wd > thr) - (wd < -thr);
                        p |= ((unsigned)(q & 255)) << (8*e);
                    }
                    pv[d] = (int)p;
                }
            }
            *reinterpret_cast<i32x4*>(&Bls[kslot][row][0]) = pv;
        }
        if constexpr (GATE) {
#pragma unroll
            for (int c = 0; c < 2; ++c) {
                int idx = tid + c*256;
                int row = idx & 127, kslot = idx >> 7;
                i32x4 pv = {0,0,0,0};
                if (n0 + row < N) {
                    const float* wp = W + (size_t)(n0+row+N)*K + kt + kslot*16;
#pragma unroll
                    for (int d = 0; d < 4; ++d) {
                        float4 wv = *reinterpret_cast<const float4*>(wp + d*4);
                        float we[4] = {wv.x, wv.y, wv.z, wv.w};
                        unsigned p = 0;
#pragma unroll
                        for (int e = 0; e < 4; ++e) {
                            double wd = (double)we[e];
                            int q = (wd > thr) - (wd < -thr);
                            p |= ((unsigned)(q & 255)) << (8*e);
                        }
                        pv[d] = (int)p;
                    }
                }
                *reinterpret_cast<i32x4*>(&B2ls[kslot][row][0]) = pv;
            }
        }
        __syncthreads();
        i32x4 a[4];
#pragma unroll
        for (int i = 0; i < 4; ++i)
            a[i] = *reinterpret_cast<const i32x4*>(&Als[ks][wr*64 + i*16 + fr][0]);
#pragma unroll
        for (int j = 0; j < 4; ++j) {
            i32x4 b = *reinterpret_cast<const i32x4*>(&Bls[ks][wc*64 + j*16 + fr][0]);
#pragma unroll
            for (int i = 0; i < 4; ++i)
                acc[i][j] = __builtin_amdgcn_mfma_i32_16x16x64_i8(a[i], b, acc[i][j], 0, 0, 0);
            if constexpr (GATE) {
                i32x4 b2 = *reinterpret_cast<const i32x4*>(&B2ls[ks][wc*64 + j*16 + fr][0]);
#pragma unroll
                for (int i = 0; i < 4; ++i)
                    acc2[i][j] = __builtin_amdgcn_mfma_i32_16x16x64_i8(a[i], b2, acc2[i][j], 0, 0, 0);
            }
        }
        __syncthreads();
    }

    // epilogue: f64 dequant.  C/D map: col=lane&15, row=(lane>>4)*4+reg
#pragma unroll
    for (int i = 0; i < 4; ++i) {
#pragma unroll
        for (int r = 0; r < 4; ++r) {
            int row = m0 + wr*64 + i*16 + (lane>>4)*4 + r;
            if (row >= M) continue;
            double mul = dqw / ascale[row];
#pragma unroll
            for (int j = 0; j < 4; ++j) {
                int col = n0 + wc*64 + j*16 + (lane & 15);
                if (col >= N) continue;
                size_t o = (size_t)row*N + col;
                if constexpr (GATE) {
                    double g = (double)acc[i][j][r] * mul;
                    double y = (double)acc2[i][j][r] * mul;
                    C[o] = g/(1.0+exp(-g)) * y;
                } else {
                    double v = (double)acc[i][j][r] * mul;
                    if (bias) v += (double)bias[col];
                    C[o] = accum ? C[o] + v : v;
                }
            }
        }
    }
}

// ---------------------------------------------------------------------------
extern "C" void kernel_launch(void* const* d_in, const int* in_sizes, int n_in,
                              void* d_out, int out_size, void* d_ws, size_t ws_size,
                              hipStream_t stream)
{
    (void)in_sizes; (void)n_in; (void)out_size;
    auto in = [&](int i){ return (const float*)d_in[i]; };

    const float *X = in(0), *T = in(1), *Y = in(2), *XC = in(3), *REF = in(4);
    const float *xe_w = in(6), *xe_b = in(7), *pos = in(8);
    const float *te_w1 = in(9), *te_b1 = in(10), *te_w2 = in(11), *te_b2 = in(12);
    const float *pp_w = in(13), *pp_b = in(14);
    const float *sa_pe_w = in(15), *sa_pe_b = in(16);
    const float *sa_ln_g = in(17), *sa_ln_b = in(18);
    const float *sa_gate_w = in(19), *sa_down_w = in(20);
    const float *sa_dc_w = in(21), *sa_dc_b = in(22);
    const float *ada_w = in(23), *ada_b = in(24);
    const float *sa_wi = in(25), *sa_wf = in(26), *sa_wg = in(27), *sa_wo = in(28);
    const float *mv_wi = in(29), *mv_wf = in(30), *mv_wg = in(31), *mv_wo = in(32);
    const float *rf_wi = in(33), *rf_wf = in(34), *rf_wg = in(35), *rf_wo = in(36);
    const float *gate_w = in(37), *down_w = in(38);
    const float *fl_w = in(39), *fl_b = in(40), *fl_ada_w = in(41), *fl_ada_b = in(42);
    float* OUT = (float*)d_out;

    // ---------- workspace layout (all main buffers f64) ----------
    size_t off = 0;
    auto AL = [&](size_t bytes){ off = (off+255)&~(size_t)255; size_t r = off; off += bytes; return r; };
    const size_t oScale = AL(37*8);
    const size_t oPart  = AL(37*32*8);
    const size_t oSM1 = AL(8*1152*8), oSM2 = AL(8*1152*8), oSM3 = AL(8*1152*8);
    const size_t oCB  = AL(8*1152*8);
    const size_t oMOD = AL(8*6912*8);
    const size_t oH   = AL((size_t)8192*1152*8);    // 75.5 MB
    const size_t oINT = AL((size_t)1024*4608*8);    // 37.7 MB (1024-row chunks)
    const size_t oF0  = AL((size_t)2048*1152*8);    // also ACC in block loop
    const size_t oXT  = AL((size_t)2048*1152*8);
    const size_t oFB  = AL((size_t)2048*1152*8);
    const size_t oIB  = AL((size_t)2048*1152*8);    // scan output in place; MLP out
    const size_t oGB  = AL((size_t)2048*1152*8);
    const size_t oRO  = AL((size_t)512*1152*8);
    const size_t oQ8X = AL((size_t)2048*1152);
    const size_t oQ8I = AL((size_t)1024*4608);
    const size_t oQ8O = AL((size_t)2048*1152);
    const size_t oQ8R = AL((size_t)512*1152);
    const size_t oQ8T = AL((size_t)8*1152);
    const size_t oQ8C = AL((size_t)8*1152);
    const size_t oDSX = AL(2048*8), oDSI = AL(1024*8), oDSO = AL(2048*8);
    const size_t oDSR = AL(512*8),  oDST = AL(8*8),    oDSC = AL(8*8);
    if (off > ws_size) return;

    char* w8 = (char*)d_ws;
    double* scales = (double*)(w8 + oScale);
    double* parts  = (double*)(w8 + oPart);
    double *SM1=(double*)(w8+oSM1), *SM2=(double*)(w8+oSM2), *SM3=(double*)(w8+oSM3);
    double *CB=(double*)(w8+oCB), *MOD=(double*)(w8+oMOD);
    double *H=(double*)(w8+oH), *INT=(double*)(w8+oINT);
    double *F0=(double*)(w8+oF0), *XT=(double*)(w8+oXT);
    double *FB=(double*)(w8+oFB), *IB=(double*)(w8+oIB), *GB=(double*)(w8+oGB);
    double *ACC=F0, *OB=IB, *RO=(double*)(w8+oRO);
    signed char *Q8X=(signed char*)(w8+oQ8X), *Q8I=(signed char*)(w8+oQ8I);
    signed char *Q8O=(signed char*)(w8+oQ8O), *Q8R=(signed char*)(w8+oQ8R);
    signed char *Q8T=(signed char*)(w8+oQ8T), *Q8C=(signed char*)(w8+oQ8C);
    double *DSX=(double*)(w8+oDSX), *DSI=(double*)(w8+oDSI), *DSO=(double*)(w8+oDSO);
    double *DSR=(double*)(w8+oDSR), *DST=(double*)(w8+oDST), *DSC=(double*)(w8+oDSC);

    // ---------- weight scales: 2 dispatches ----------
    WList wl{};
    long long wn[37];
    int nw = 0;
    auto addw = [&](const float* w, long long n){ wl.p[nw]=w; wl.n[nw]=n; wn[nw]=n; nw++; };
    addw(te_w1, 294912); addw(te_w2, 1327104); addw(pp_w, 884736);
    addw(sa_gate_w, 10616832); addw(sa_down_w, 5308416);
    for (int l = 0; l < 2; ++l) {
        addw(ada_w + (size_t)l*7962624, 7962624);
        addw(sa_wi + (size_t)l*1327104, 1327104);
        addw(sa_wf + (size_t)l*1327104, 1327104);
        addw(sa_wg + (size_t)l*1327104, 1327104);
        addw(sa_wo + (size_t)l*1327104, 1327104);
        addw(mv_wi + (size_t)l*1327104, 1327104);
        addw(mv_wf + (size_t)l*1327104, 1327104);
        addw(mv_wg + (size_t)l*1327104, 1327104);
        addw(mv_wo + (size_t)l*1327104, 1327104);
        addw(rf_wi + (size_t)l*1327104, 1327104);
        addw(rf_wf + (size_t)l*1327104, 1327104);
        addw(rf_wg + (size_t)l*1327104, 1327104);
        addw(rf_wo + (size_t)l*1327104, 1327104);
        addw(gate_w + (size_t)l*10616832, 10616832);
        addw(down_w + (size_t)l*5308416, 5308416);
    }
    addw(fl_ada_w, 2654208); addw(fl_w, 36864);
    k_abssum_all<<<dim3(32,37), 256, 0, stream>>>(wl, parts);
    k_abssum_fin<<<37, 64, 0, stream>>>(parts, scales);

    // ---------- launch helpers ----------
    auto qgemm = [&](const signed char* A8, const double* as, const float* Win, int slot,
                     const float* b, double* Cout, int M, int N, int K, int accum){
        dim3 g((unsigned)((M+127)/128), (unsigned)((N+127)/128));
        k_qgemm<0><<<g, 256, 0, stream>>>(A8, as, Win, scales+slot, wn[slot], b, Cout, M, N, K, accum);
    };
    auto qgemmGate = [&](const signed char* A8, const double* as, const float* Win, int slot,
                         double* Cout, int M){
        dim3 g((unsigned)((M+127)/128), 36u);
        k_qgemm<1><<<g, 256, 0, stream>>>(A8, as, Win, scales+slot, wn[slot], nullptr, Cout, M, 4608, 1152, 0);
    };

    // ---------- conditioning vector c ----------
    k_temb<<<8, 128, 0, stream>>>(T, SM1);
    k_rsq8<double><<<8, 256, 256*8, stream>>>(SM1, Q8T, DST, 256, 0);
    qgemm(Q8T, DST, te_w1, 0, te_b1, SM3, 8, 1152, 256, 0);
    k_rsq8<double><<<8, 256, 1152*8, stream>>>(SM3, Q8T, DST, 1152, 1);
    qgemm(Q8T, DST, te_w2, 1, te_b2, SM2, 8, 1152, 1152, 0);
    k_rsq8<float><<<8, 256, 768*8, stream>>>(Y, Q8T, DST, 768, 0);
    qgemm(Q8T, DST, pp_w, 2, pp_b, SM3, 8, 1152, 768, 0);
    k_add<<<36, 256, 0, stream>>>(SM2, SM3, CB, 9216);
    k_rsq8<double><<<8, 256, 1152*8, stream>>>(CB, Q8C, DSC, 1152, 1);

    // ---------- spatial adapter: patch embed + block 0 only ----------
    k_dgemm<1,0><<<dim3(18,128), 256, 0, stream>>>(XC, sa_pe_w, sa_pe_b, H, 8192, 1152, 1536);
    for (int ch = 0; ch < 8; ++ch) {
        double* Hrow = H + (size_t)ch*1024*1152;
        k_lnq8<<<1024, 256, 1152*8, stream>>>(Hrow, Q8X, DSX, 1152, sa_ln_g, sa_ln_b,
                                              nullptr, nullptr, 0, 1e-5);
        qgemmGate(Q8X, DSX, sa_gate_w, 3, INT, 1024);
        k_rsq8<double><<<1024, 256, 4608*8, stream>>>(INT, Q8I, DSI, 4608, 0);
        qgemm(Q8I, DSI, sa_down_w, 4, nullptr, Hrow, 1024, 1152, 4608, 0);
    }
    k_dgemm<2,1><<<dim3(18,32), 256, 0, stream>>>(H, sa_dc_w, sa_dc_b, F0, 2048, 1152, 4608);

    // ---------- patchify latents + pos + feats0 ----------
    k_patchify<<<9216, 256, 0, stream>>>(X, xe_w, xe_b, pos, F0, XT);
    k_rsq8<float><<<512, 256, 1152*8, stream>>>(REF, Q8R, DSR, 1152, 0);

    // ---------- transformer blocks ----------
    for (int l = 0; l < 2; ++l) {
        int sb = 5 + l*15;
        const float *wada = ada_w + (size_t)l*7962624, *bada = ada_b + (size_t)l*6912;
        const float *swi = sa_wi + (size_t)l*1327104, *swf = sa_wf + (size_t)l*1327104;
        const float *swg = sa_wg + (size_t)l*1327104, *swo = sa_wo + (size_t)l*1327104;
        const float *mwi = mv_wi + (size_t)l*1327104, *mwf = mv_wf + (size_t)l*1327104;
        const float *mwg = mv_wg + (size_t)l*1327104, *mwo = mv_wo + (size_t)l*1327104;
        const float *rwi = rf_wi + (size_t)l*1327104, *rwf = rf_wf + (size_t)l*1327104;
        const float *rwg = rf_wg + (size_t)l*1327104, *rwo = rf_wo + (size_t)l*1327104;
        const float *wgt = gate_w + (size_t)l*10616832, *wdn = down_w + (size_t)l*5308416;

        qgemm(Q8C, DSC, wada, sb+0, bada, MOD, 8, 6912, 1152, 0);

        k_lnq8<<<2048, 256, 1152*8, stream>>>(XT, Q8X, DSX, 1152, nullptr, nullptr,
                                              MOD+0, MOD+1152, 6912, 1e-6);

        // self attention (seq = 256 tokens)
        qgemm(Q8X, DSX, swf, sb+2, nullptr, FB, 2048, 1152, 1152, 0);
        qgemm(Q8X, DSX, swi, sb+1, nullptr, IB, 2048, 1152, 1152, 0);
        qgemm(Q8X, DSX, swg, sb+3, nullptr, GB, 2048, 1152, 1152, 0);
        k_scan<<<36, 256, 0, stream>>>(FB, IB, OB, 8, 294912LL, 1152, 1152LL, 256);
        k_ogateq8<<<2048, 256, 1152*8, stream>>>(OB, GB, Q8O, DSO, 1152);
        qgemm(Q8O, DSO, swo, sb+4, nullptr, ACC, 2048, 1152, 1152, 0);

        // multi-view attention (seq = 4 views; token layout unchanged)
        qgemm(Q8X, DSX, mwf, sb+6, nullptr, FB, 2048, 1152, 1152, 0);
        qgemm(Q8X, DSX, mwi, sb+5, nullptr, IB, 2048, 1152, 1152, 0);
        qgemm(Q8X, DSX, mwg, sb+7, nullptr, GB, 2048, 1152, 1152, 0);
        k_scan<<<2304, 256, 0, stream>>>(FB, IB, OB, 2, 1179648LL, 294912, 294912LL, 4);
        k_ogateq8<<<2048, 256, 1152*8, stream>>>(OB, GB, Q8O, DSO, 1152);
        qgemm(Q8O, DSO, mwo, sb+8, nullptr, ACC, 2048, 1152, 1152, 1);   // +=

        // ref attention on 2 unique batches
        qgemm(Q8R, DSR, rwf, sb+10, nullptr, FB, 512, 1152, 1152, 0);
        qgemm(Q8R, DSR, rwi, sb+9,  nullptr, IB, 512, 1152, 1152, 0);
        qgemm(Q8R, DSR, rwg, sb+11, nullptr, GB, 512, 1152, 1152, 0);
        k_scan<<<9, 256, 0, stream>>>(FB, IB, OB, 2, 294912LL, 1152, 1152LL, 256);
        k_ogateq8<<<512, 256, 1152*8, stream>>>(OB, GB, Q8O, DSO, 1152);
        qgemm(Q8O, DSO, rwo, sb+12, nullptr, RO, 512, 1152, 1152, 0);

        k_resid_attn<<<9216, 256, 0, stream>>>(XT, ACC, RO, MOD);

        // MLP (1024-row chunks through INT)
        k_lnq8<<<2048, 256, 1152*8, stream>>>(XT, Q8X, DSX, 1152, nullptr, nullptr,
                                              MOD+3*1152, MOD+4*1152, 6912, 1e-6);
        for (int ch = 0; ch < 2; ++ch) {
            qgemmGate(Q8X + (size_t)ch*1024*1152, DSX + ch*1024, wgt, sb+13, INT, 1024);
            k_rsq8<double><<<1024, 256, 4608*8, stream>>>(INT, Q8I, DSI, 4608, 0);
            qgemm(Q8I, DSI, wdn, sb+14, nullptr, OB + (size_t)ch*1024*1152, 1024, 1152, 4608, 0);
        }
        k_resid_mlp<<<9216, 256, 0, stream>>>(XT, OB, MOD);
    }

    // ---------- final layer + unpatchify ----------
    qgemm(Q8C, DSC, fl_ada_w, 35, fl_ada_b, MOD, 8, 2304, 1152, 0);
    k_lnq8<<<2048, 256, 1152*8, stream>>>(XT, Q8X, DSX, 1152, nullptr, nullptr,
                                          MOD+0, MOD+1152, 2304, 1e-6);
    qgemm(Q8X, DSX, fl_w, 36, fl_b, FB, 2048, 32, 1152, 0);
    k_unpatch<<<256, 256, 0, stream>>>(FB, OUT);
}

// Round 6
// 6283.830 us; speedup vs baseline: 1.9795x; 1.3954x over previous
//
#include <hip/hip_runtime.h>

#define DEV __device__ __forceinline__

typedef __attribute__((ext_vector_type(4))) int i32x4;

// ---------------------------------------------------------------------------
// TernaryMVAdapter forward on MI355X. Round 5: round-3 f64-exact pipeline
//  + weights pre-ternarized once to int8 (bit-identical decisions)
//  + HGRN scan split (parallel sigmoid/silu precompute + lean serial chain)
//  - convs stay on the PROVEN SIMT f64 k_dgemm (round-4's mfma_f64 16x16x4
//    fragment-layout assumption corrupted F0 -> absmax 2.27; do not reuse
//    without a verified f64 fragment map).
// ---------------------------------------------------------------------------

struct WList { const float* p[37]; long long n[37]; };
struct WOffs { long long o[37]; };

// ---------------- fused deterministic |w| sums (37 slots) ------------------
__global__ void k_abssum_all(WList wl, double* __restrict__ partials)
{
    const int slot = blockIdx.y;
    const float* w = wl.p[slot];
    const long long n = wl.n[slot];
    __shared__ double sm[256];
    double s = 0.0;
    for (long long i = (long long)blockIdx.x*256 + threadIdx.x; i < n; i += 32LL*256)
        s += (double)fabsf(w[i]);
    sm[threadIdx.x] = s;
    __syncthreads();
    for (int k = 128; k > 0; k >>= 1) {
        if ((int)threadIdx.x < k) sm[threadIdx.x] += sm[threadIdx.x + k];
        __syncthreads();
    }
    if (threadIdx.x == 0) partials[slot*32 + blockIdx.x] = sm[0];
}

__global__ void k_abssum_fin(const double* __restrict__ partials, double* __restrict__ out)
{
    const int slot = blockIdx.x;
    if (threadIdx.x == 0) {
        double s = 0.0;
        for (int i = 0; i < 32; ++i) s += partials[slot*32 + i];
        out[slot] = s;
    }
}

// ---------------- one-time weight ternarization (f64-exact decision) -------
__global__ void k_ternarize(WList wl, WOffs wo, const double* __restrict__ scales,
                            signed char* __restrict__ W8)
{
    const int slot = blockIdx.y;
    const float* w = wl.p[slot];
    const long long n4 = wl.n[slot] >> 2;           // all sizes divisible by 4
    const double dqw = fmax(scales[slot] / (double)wl.n[slot], 1e-5);
    const double thr = 0.5 * dqw;
    signed char* o = W8 + wo.o[slot];
    for (long long i = (long long)blockIdx.x*256 + threadIdx.x; i < n4; i += 64LL*256) {
        float4 v = *reinterpret_cast<const float4*>(w + i*4);
        float we[4] = {v.x, v.y, v.z, v.w};
        char r[4];
#pragma unroll
        for (int e = 0; e < 4; ++e) {
            double wd = (double)we[e];
            r[e] = (char)((wd > thr) - (wd < -thr));
        }
        *reinterpret_cast<char4*>(o + i*4) = make_char4(r[0], r[1], r[2], r[3]);
    }
}

// ---------------- timestep frequency embedding (f64) -----------------------
__global__ void k_temb(const float* __restrict__ t, double* __restrict__ out)
{
    int b = blockIdx.x, j = threadIdx.x;               // 8 x 128
    double fr  = exp(-9.210340371976184 * (double)j / 128.0);
    double ang = (double)t[b] * fr;
    out[b*256 + j]       = cos(ang);
    out[b*256 + 128 + j] = sin(ang);
}

// ---------------- rmsnorm + int8 absmax quant (f64) ------------------------
template<typename TI>
__global__ void k_rsq8(const TI* __restrict__ x, signed char* __restrict__ q8,
                       double* __restrict__ dscale, int K, int pre_silu)
{
    extern __shared__ double rb[];
    __shared__ double red[256], red2[256];
    const int row = blockIdx.x, tid = threadIdx.x;
    const TI* xr = x + (size_t)row*K;
    double ss = 0.0, am = 0.0;
    for (int i = tid; i < K; i += 256) {
        double v = (double)xr[i];
        if (pre_silu) v = v / (1.0 + exp(-v));
        rb[i] = v; ss += v*v; am = fmax(am, fabs(v));
    }
    red[tid] = ss; red2[tid] = am;
    __syncthreads();
    for (int s = 128; s > 0; s >>= 1) {
        if (tid < s) { red[tid] += red[tid+s]; red2[tid] = fmax(red2[tid], red2[tid+s]); }
        __syncthreads();
    }
    double rms = 1.0 / sqrt(red[0]/(double)K + 1e-8);
    double s   = 127.0 / fmax(red2[0]*rms, 1e-5);
    signed char* orow = q8 + (size_t)row*K;
    for (int i = tid; i < K; i += 256)
        orow[i] = (signed char)(int)fmin(fmax(rint(rb[i]*rms*s), -128.0), 127.0);
    if (tid == 0) dscale[row] = s;
}

// ---------------- layernorm(+gb/+mod) + rmsnorm + int8 quant (f64) ---------
__global__ void k_lnq8(const double* __restrict__ x, signed char* __restrict__ q8,
                       double* __restrict__ dscale, int K,
                       const float* __restrict__ gamma, const float* __restrict__ beta,
                       const double* __restrict__ sh, const double* __restrict__ sc,
                       int modstride, double eps)
{
    extern __shared__ double rb[];
    __shared__ double red[256], red2[256];
    const int row = blockIdx.x, tid = threadIdx.x;
    const double* xr = x + (size_t)row*K;
    double s1 = 0.0;
    for (int i = tid; i < K; i += 256) { double v = xr[i]; rb[i] = v; s1 += v; }
    red[tid] = s1; __syncthreads();
    for (int s = 128; s > 0; s >>= 1) { if (tid < s) red[tid] += red[tid+s]; __syncthreads(); }
    double mu = red[0]/(double)K;
    __syncthreads();
    double s2 = 0.0;
    for (int i = tid; i < K; i += 256) { double d = rb[i]-mu; s2 += d*d; }
    red[tid] = s2; __syncthreads();
    for (int s = 128; s > 0; s >>= 1) { if (tid < s) red[tid] += red[tid+s]; __syncthreads(); }
    double r = 1.0 / sqrt(red[0]/(double)K + eps);
    const int bn = row >> 8;
    __syncthreads();
    double ss = 0.0, am = 0.0;
    for (int i = tid; i < K; i += 256) {
        double y = (rb[i]-mu)*r;
        if (gamma) y = y*(double)gamma[i] + (double)beta[i];
        if (sh)    y = y*(1.0 + sc[(size_t)bn*modstride + i]) + sh[(size_t)bn*modstride + i];
        rb[i] = y; ss += y*y; am = fmax(am, fabs(y));
    }
    red[tid] = ss; red2[tid] = am;
    __syncthreads();
    for (int s = 128; s > 0; s >>= 1) {
        if (tid < s) { red[tid] += red[tid+s]; red2[tid] = fmax(red2[tid], red2[tid+s]); }
        __syncthreads();
    }
    double rms = 1.0 / sqrt(red[0]/(double)K + 1e-8);
    double s   = 127.0 / fmax(red2[0]*rms, 1e-5);
    signed char* orow = q8 + (size_t)row*K;
    for (int i = tid; i < K; i += 256)
        orow[i] = (signed char)(int)fmin(fmax(rint(rb[i]*rms*s), -128.0), 127.0);
    if (tid == 0) dscale[row] = s;
}

// ---------------- ogate (rmsnorm*g*sig(g)) + rmsnorm + quant (f64) ---------
__global__ void k_ogateq8(const double* __restrict__ O, const double* __restrict__ G,
                          signed char* __restrict__ q8, double* __restrict__ dscale, int K)
{
    extern __shared__ double rb[];
    __shared__ double red[256], red2[256];
    const int row = blockIdx.x, tid = threadIdx.x;
    const double* orow = O + (size_t)row*K;
    const double* grow = G + (size_t)row*K;
    double ss = 0.0;
    for (int i = tid; i < K; i += 256) { double v = orow[i]; rb[i] = v; ss += v*v; }
    red[tid] = ss; __syncthreads();
    for (int s = 128; s > 0; s >>= 1) { if (tid < s) red[tid] += red[tid+s]; __syncthreads(); }
    double rmso = 1.0 / sqrt(red[0]/(double)K + 1e-8);
    __syncthreads();
    double ss2 = 0.0, am = 0.0;
    for (int i = tid; i < K; i += 256) {
        double g = grow[i];
        double y = rb[i]*rmso * g / (1.0 + exp(-g));
        rb[i] = y; ss2 += y*y; am = fmax(am, fabs(y));
    }
    red[tid] = ss2; red2[tid] = am;
    __syncthreads();
    for (int s = 128; s > 0; s >>= 1) {
        if (tid < s) { red[tid] += red[tid+s]; red2[tid] = fmax(red2[tid], red2[tid+s]); }
        __syncthreads();
    }
    double rms = 1.0 / sqrt(red[0]/(double)K + 1e-8);
    double s   = 127.0 / fmax(red2[0]*rms, 1e-5);
    signed char* qrow = q8 + (size_t)row*K;
    for (int i = tid; i < K; i += 256)
        qrow[i] = (signed char)(int)fmin(fmax(rint(rb[i]*rms*s), -128.0), 127.0);
    if (tid == 0) dscale[row] = s;
}

// ---------------- HGRN gate precompute + lean serial scan ------------------
__global__ void k_gatepre(double* __restrict__ F, double* __restrict__ I, long long n)
{
    long long i = (long long)blockIdx.x*256 + threadIdx.x;
    if (i >= n) return;
    double fp = F[i], ip = I[i];
    double f = 1.0/(1.0+exp(-fp));
    double v = (ip/(1.0+exp(-ip)))*(1.0-f);
    F[i] = f; I[i] = v;
}

__global__ void k_scan2(const double* __restrict__ F, const double* __restrict__ V,
                        double* __restrict__ O, int n_outer, long long outer_stride,
                        int n_inner, long long t_stride, int T)
{
    long long chain = (long long)blockIdx.x*blockDim.x + threadIdx.x;
    if (chain >= (long long)n_outer*n_inner) return;
    long long base = (chain / n_inner)*outer_stride + (chain % n_inner);
    double h = 0.0;
    for (int t = 0; t < T; ++t) {
        long long idx = base + (long long)t*t_stride;
        h = F[idx]*h + V[idx];
        O[idx] = h;
    }
}

// ---------------- misc elementwise (f64) -----------------------------------
__global__ void k_add(const double* __restrict__ a, const double* __restrict__ b,
                      double* __restrict__ o, int n)
{
    int i = blockIdx.x*256 + threadIdx.x;
    if (i < n) o[i] = a[i] + b[i];
}

__global__ void k_resid_attn(double* __restrict__ xt, const double* __restrict__ acc,
                             const double* __restrict__ refo, const double* __restrict__ mod)
{
    int idx = blockIdx.x*256 + threadIdx.x;            // 2048*1152 exact
    int r = idx / 1152, d = idx - r*1152;
    int bn = r >> 8, l = r & 255;
    double ga = mod[(size_t)bn*6912 + 2*1152 + d];
    double rv = refo[((size_t)((bn>>2)*256 + l))*1152 + d];
    xt[idx] += ga*(acc[idx] + rv);
}

__global__ void k_resid_mlp(double* __restrict__ xt, const double* __restrict__ t2,
                            const double* __restrict__ mod)
{
    int idx = blockIdx.x*256 + threadIdx.x;
    int r = idx / 1152, d = idx - r*1152;
    int bn = r >> 8;
    xt[idx] += mod[(size_t)bn*6912 + 5*1152 + d] * t2[idx];
}

// xt = patchify(x)@xe_w + xe_b + pos + feats0   (f64)
__global__ void k_patchify(const float* __restrict__ x, const float* __restrict__ w,
                           const float* __restrict__ bias, const float* __restrict__ pos,
                           const double* __restrict__ f0, double* __restrict__ xt)
{
    int idx = blockIdx.x*256 + threadIdx.x;            // 2048*1152 exact
    int r = idx / 1152, o = idx - r*1152;
    int bn = r >> 8, p = r & 255;
    int y = p >> 4, xx = p & 15;
    double acc = (double)bias[o] + (double)pos[(size_t)p*1152 + o] + f0[idx];
#pragma unroll
    for (int c = 0; c < 4; ++c)
#pragma unroll
        for (int ky = 0; ky < 2; ++ky)
#pragma unroll
            for (int kx = 0; kx < 2; ++kx)
                acc += (double)x[((size_t)(bn*4 + c)*32 + 2*y+ky)*32 + 2*xx+kx]
                     * (double)w[o*16 + c*4 + ky*2 + kx];
    xt[idx] = acc;
}

__global__ void k_unpatch(const double* __restrict__ flo, float* __restrict__ out)
{
    int idx = blockIdx.x*256 + threadIdx.x;            // 65536 exact
    int xx = idx & 31, y = (idx>>5)&31, ch = (idx>>10)&7, b = idx>>13;
    int hp = y>>1, py = y&1, wp = xx>>1, px = xx&1;
    out[idx] = (float)flo[((size_t)(b*256 + hp*16 + wp))*32 + (py*2+px)*8 + ch];
}

// ---------------- f64 SIMT GEMM for the two plain convs (PROVEN, round 3) --
template<int AMODE>
DEV void load_a4d(const void* __restrict__ A, int row, int k, int M, double o[4])
{
    if (row >= M) { o[0]=o[1]=o[2]=o[3]=0.0; return; }
    if constexpr (AMODE == 1) {
        const float* Af = (const float*)A;
        int b = row>>10, p = row&1023, oy = p>>5, ox = p&31;
        int c = k>>8, ky = (k>>4)&15, kx = k&15;
        float4 v = *reinterpret_cast<const float4*>(
            Af + (((size_t)(b*6+c)*512 + (size_t)(oy*16+ky))*512 + (size_t)(ox*16+kx)));
        o[0]=v.x; o[1]=v.y; o[2]=v.z; o[3]=v.w;
    } else {
        const double* Ad = (const double*)A;
        int b = row>>8, y = (row>>4)&15, x = row&15;
        int q = k/1152, c = k - q*1152, ky = q>>1, kx = q&1;
        const double* p = Ad + (size_t)(b*1024 + (2*y+ky)*32 + 2*x+kx)*1152 + c;
        o[0]=p[0]; o[1]=p[1]; o[2]=p[2]; o[3]=p[3];
    }
}

template<int WMODE>
DEV void load_w4d(const float* __restrict__ W, int row, int k, int Nb, int K, double o[4])
{
    if (row >= Nb) { o[0]=o[1]=o[2]=o[3]=0.0; return; }
    if constexpr (WMODE == 0) {
        float4 v = *reinterpret_cast<const float4*>(W + (size_t)row*K + k);
        o[0]=v.x; o[1]=v.y; o[2]=v.z; o[3]=v.w;
    } else {
        int q = k/1152, c = k - q*1152;
        const float* p = W + (size_t)row*4608 + (size_t)c*4 + q;
        o[0]=p[0]; o[1]=p[4]; o[2]=p[8]; o[3]=p[12];
    }
}

template<int AMODE, int WMODE>
__global__ __launch_bounds__(256)
void k_dgemm(const void* __restrict__ A, const float* __restrict__ W,
             const float* __restrict__ bias, double* __restrict__ C,
             int M, int N, int K)
{
    __shared__ double As[16][64];
    __shared__ double Ws[16][64];
    const int tid = threadIdx.x;
    const int tx = tid & 15, ty = tid >> 4;
    const int m0 = blockIdx.y*64, n0 = blockIdx.x*64;
    const int lr = tid >> 2;
    const int lc = (tid & 3) * 4;

    double acc[4][4] = {};

    for (int kt = 0; kt < K; kt += 16) {
        {
            double v[4];
            load_a4d<AMODE>(A, m0+lr, kt+lc, M, v);
            As[lc+0][lr]=v[0]; As[lc+1][lr]=v[1]; As[lc+2][lr]=v[2]; As[lc+3][lr]=v[3];
        }
        {
            double wv[4];
            load_w4d<WMODE>(W, n0+lr, kt+lc, N, K, wv);
            Ws[lc+0][lr]=wv[0]; Ws[lc+1][lr]=wv[1]; Ws[lc+2][lr]=wv[2]; Ws[lc+3][lr]=wv[3];
        }
        __syncthreads();
#pragma unroll
        for (int k = 0; k < 16; ++k) {
            double a[4], b[4];
#pragma unroll
            for (int e = 0; e < 4; ++e) { a[e] = As[k][ty*4+e]; b[e] = Ws[k][tx*4+e]; }
#pragma unroll
            for (int i = 0; i < 4; ++i)
#pragma unroll
                for (int j = 0; j < 4; ++j) acc[i][j] += a[i]*b[j];
        }
        __syncthreads();
    }

#pragma unroll
    for (int i = 0; i < 4; ++i) {
        int row = m0 + ty*4 + i;
        if (row >= M) continue;
#pragma unroll
        for (int j = 0; j < 4; ++j) {
            int col = n0 + tx*4 + j;
            if (col >= N) continue;
            C[(size_t)row*N + col] = acc[i][j] + (bias ? (double)bias[col] : 0.0);
        }
    }
}

// ---------------- int8 MFMA GEMM (exact), f64 dequant ----------------------
// PRE=1: W8 = pre-ternarized int8 [N(,2N)][K]; PRE=0: ternarize Wf on the fly.
template<int GATE, int PRE>
__global__ __launch_bounds__(256)
void k_qgemm(const signed char* __restrict__ A8, const double* __restrict__ ascale,
             const float* __restrict__ Wf, const signed char* __restrict__ W8,
             const double* __restrict__ wsum, long long wcount,
             const float* __restrict__ bias, double* __restrict__ C,
             int M, int N, int K, int accum)
{
    __shared__ __align__(16) signed char Als[4][128][16];
    __shared__ __align__(16) signed char Bls[4][128][16];
    __shared__ __align__(16) signed char B2ls[GATE?4:1][GATE?128:1][16];
    const int tid = threadIdx.x;
    const int lane = tid & 63, wid = tid >> 6;
    const int wr = wid >> 1, wc = wid & 1;             // 2x2 waves, 64x64 each
    const int m0 = blockIdx.x*128, n0 = blockIdx.y*128;
    const int ks = lane >> 4, fr = lane & 15;

    const double dqw = fmax(*wsum / (double)wcount, 1e-5);  // mean|w|
    const double thr = 0.5 * dqw;                           // ternary threshold

    i32x4 acc[4][4];
    i32x4 acc2[GATE?4:1][4];
#pragma unroll
    for (int i = 0; i < 4; ++i)
#pragma unroll
        for (int j = 0; j < 4; ++j) {
            acc[i][j] = i32x4{0,0,0,0};
            if constexpr (GATE) acc2[i][j] = i32x4{0,0,0,0};
        }

    for (int kt = 0; kt < K; kt += 64) {
#pragma unroll
        for (int c = 0; c < 2; ++c) {
            int idx = tid + c*256;
            int row = idx & 127, kslot = idx >> 7;
            i32x4 v = {0,0,0,0};
            if (m0 + row < M)
                v = *reinterpret_cast<const i32x4*>(A8 + (size_t)(m0+row)*K + kt + kslot*16);
            *reinterpret_cast<i32x4*>(&Als[kslot][row][0]) = v;
        }
#pragma unroll
        for (int c = 0; c < 2; ++c) {
            int idx = tid + c*256;
            int row = idx & 127, kslot = idx >> 7;
            i32x4 pv = {0,0,0,0};
            if (n0 + row < N) {
                if constexpr (PRE) {
                    pv = *reinterpret_cast<const i32x4*>(W8 + (size_t)(n0+row)*K + kt + kslot*16);
                } else {
                    const float* wp = Wf + (size_t)(n0+row)*K + kt + kslot*16;
#pragma unroll
                    for (int d = 0; d < 4; ++d) {
                        float4 wv = *reinterpret_cast<const float4*>(wp + d*4);
                        float we[4] = {wv.x, wv.y, wv.z, wv.w};
                        unsigned p = 0;
#pragma unroll
                        for (int e = 0; e < 4; ++e) {
                            double wd = (double)we[e];
                            int q = (wd > thr) - (wd < -thr);
                            p |= ((unsigned)(q & 255)) << (8*e);
                        }
                        pv[d] = (int)p;
                    }
                }
            }
            *reinterpret_cast<i32x4*>(&Bls[kslot][row][0]) = pv;
        }
        if constexpr (GATE) {
#pragma unroll
            for (int c = 0; c < 2; ++c) {
                int idx = tid + c*256;
                int row = idx & 127, kslot = idx >> 7;
                i32x4 pv = {0,0,0,0};
                if (n0 + row < N) {
                    if constexpr (PRE) {
                        pv = *reinterpret_cast<const i32x4*>(W8 + (size_t)(n0+row+N)*K + kt + kslot*16);
                    } else {
                        const float* wp = Wf + (size_t)(n0+row+N)*K + kt + kslot*16;
#pragma unroll
                        for (int d = 0; d < 4; ++d) {
                            float4 wv = *reinterpret_cast<const float4*>(wp + d*4);
                            float we[4] = {wv.x, wv.y, wv.z, wv.w};
                            unsigned p = 0;
#pragma unroll
                            for (int e = 0; e < 4; ++e) {
                                double wd = (double)we[e];
                                int q = (wd > thr) - (wd < -thr);
                                p |= ((unsigned)(q & 255)) << (8*e);
                            }
                            pv[d] = (int)p;
                        }
                    }
                }
                *reinterpret_cast<i32x4*>(&B2ls[kslot][row][0]) = pv;
            }
        }
        __syncthreads();
        i32x4 a[4];
#pragma unroll
        for (int i = 0; i < 4; ++i)
            a[i] = *reinterpret_cast<const i32x4*>(&Als[ks][wr*64 + i*16 + fr][0]);
#pragma unroll
        for (int j = 0; j < 4; ++j) {
            i32x4 b = *reinterpret_cast<const i32x4*>(&Bls[ks][wc*64 + j*16 + fr][0]);
#pragma unroll
            for (int i = 0; i < 4; ++i)
                acc[i][j] = __builtin_amdgcn_mfma_i32_16x16x64_i8(a[i], b, acc[i][j], 0, 0, 0);
            if constexpr (GATE) {
                i32x4 b2 = *reinterpret_cast<const i32x4*>(&B2ls[ks][wc*64 + j*16 + fr][0]);
#pragma unroll
                for (int i = 0; i < 4; ++i)
                    acc2[i][j] = __builtin_amdgcn_mfma_i32_16x16x64_i8(a[i], b2, acc2[i][j], 0, 0, 0);
            }
        }
        __syncthreads();
    }

    // epilogue: f64 dequant.  C/D map: col=lane&15, row=(lane>>4)*4+reg
#pragma unroll
    for (int i = 0; i < 4; ++i) {
#pragma unroll
        for (int r = 0; r < 4; ++r) {
            int row = m0 + wr*64 + i*16 + (lane>>4)*4 + r;
            if (row >= M) continue;
            double mul = dqw / ascale[row];
#pragma unroll
            for (int j = 0; j < 4; ++j) {
                int col = n0 + wc*64 + j*16 + (lane & 15);
                if (col >= N) continue;
                size_t o = (size_t)row*N + col;
                if constexpr (GATE) {
                    double g = (double)acc[i][j][r] * mul;
                    double y = (double)acc2[i][j][r] * mul;
                    C[o] = g/(1.0+exp(-g)) * y;
                } else {
                    double v = (double)acc[i][j][r] * mul;
                    if (bias) v += (double)bias[col];
                    C[o] = accum ? C[o] + v : v;
                }
            }
        }
    }
}

// ---------------------------------------------------------------------------
extern "C" void kernel_launch(void* const* d_in, const int* in_sizes, int n_in,
                              void* d_out, int out_size, void* d_ws, size_t ws_size,
                              hipStream_t stream)
{
    (void)in_sizes; (void)n_in; (void)out_size;
    auto in = [&](int i){ return (const float*)d_in[i]; };

    const float *X = in(0), *T = in(1), *Y = in(2), *XC = in(3), *REF = in(4);
    const float *xe_w = in(6), *xe_b = in(7), *pos = in(8);
    const float *te_w1 = in(9), *te_b1 = in(10), *te_w2 = in(11), *te_b2 = in(12);
    const float *pp_w = in(13), *pp_b = in(14);
    const float *sa_pe_w = in(15), *sa_pe_b = in(16);
    const float *sa_ln_g = in(17), *sa_ln_b = in(18);
    const float *sa_gate_w = in(19), *sa_down_w = in(20);
    const float *sa_dc_w = in(21), *sa_dc_b = in(22);
    const float *ada_w = in(23), *ada_b = in(24);
    const float *sa_wi = in(25), *sa_wf = in(26), *sa_wg = in(27), *sa_wo = in(28);
    const float *mv_wi = in(29), *mv_wf = in(30), *mv_wg = in(31), *mv_wo = in(32);
    const float *rf_wi = in(33), *rf_wf = in(34), *rf_wg = in(35), *rf_wo = in(36);
    const float *gate_w = in(37), *down_w = in(38);
    const float *fl_w = in(39), *fl_b = in(40), *fl_ada_w = in(41), *fl_ada_b = in(42);
    float* OUT = (float*)d_out;

    // ---------- workspace layout (base ~223 MB; W8 optional +101 MB) -------
    size_t off = 0;
    auto AL = [&](size_t bytes){ off = (off+255)&~(size_t)255; size_t r = off; off += bytes; return r; };
    const size_t oScale = AL(37*8);
    const size_t oPart  = AL(37*32*8);
    const size_t oSM1 = AL(8*1152*8), oSM2 = AL(8*1152*8), oSM3 = AL(8*1152*8);
    const size_t oCB  = AL(8*1152*8);
    const size_t oMOD = AL(8*6912*8);
    const size_t oH   = AL((size_t)8192*1152*8);    // 75.5 MB; reused as OB later
    const size_t oINT = AL((size_t)1024*4608*8);    // 37.7 MB (1024-row chunks)
    const size_t oF0  = AL((size_t)2048*1152*8);    // also ACC in block loop
    const size_t oXT  = AL((size_t)2048*1152*8);
    const size_t oFB  = AL((size_t)2048*1152*8);
    const size_t oIB  = AL((size_t)2048*1152*8);
    const size_t oGB  = AL((size_t)2048*1152*8);
    const size_t oRO  = AL((size_t)512*1152*8);
    const size_t oQ8X = AL((size_t)2048*1152);
    const size_t oQ8I = AL((size_t)1024*4608);
    const size_t oQ8O = AL((size_t)2048*1152);
    const size_t oQ8R = AL((size_t)512*1152);
    const size_t oQ8T = AL((size_t)8*1152);
    const size_t oQ8C = AL((size_t)8*1152);
    const size_t oDSX = AL(2048*8), oDSI = AL(1024*8), oDSO = AL(2048*8);
    const size_t oDSR = AL(512*8),  oDST = AL(8*8),    oDSC = AL(8*8);
    if (off > ws_size) return;

    // ---------- weight list + optional pre-ternarized region ----------
    WList wl{}; WOffs wo{};
    long long wn[37];
    int nw = 0;
    auto addw = [&](const float* w, long long n){ wl.p[nw]=w; wl.n[nw]=n; wn[nw]=n; nw++; };
    addw(te_w1, 294912); addw(te_w2, 1327104); addw(pp_w, 884736);
    addw(sa_gate_w, 10616832); addw(sa_down_w, 5308416);
    for (int l = 0; l < 2; ++l) {
        addw(ada_w + (size_t)l*7962624, 7962624);
        addw(sa_wi + (size_t)l*1327104, 1327104);
        addw(sa_wf + (size_t)l*1327104, 1327104);
        addw(sa_wg + (size_t)l*1327104, 1327104);
        addw(sa_wo + (size_t)l*1327104, 1327104);
        addw(mv_wi + (size_t)l*1327104, 1327104);
        addw(mv_wf + (size_t)l*1327104, 1327104);
        addw(mv_wg + (size_t)l*1327104, 1327104);
        addw(mv_wo + (size_t)l*1327104, 1327104);
        addw(rf_wi + (size_t)l*1327104, 1327104);
        addw(rf_wf + (size_t)l*1327104, 1327104);
        addw(rf_wg + (size_t)l*1327104, 1327104);
        addw(rf_wo + (size_t)l*1327104, 1327104);
        addw(gate_w + (size_t)l*10616832, 10616832);
        addw(down_w + (size_t)l*5308416, 5308416);
    }
    addw(fl_ada_w, 2654208); addw(fl_w, 36864);

    size_t off_saved = off;
    long long wtot = 0;
    for (int i = 0; i < 37; ++i) { wo.o[i] = wtot; wtot += (wn[i] + 255) & ~255LL; }
    const size_t oW8 = AL((size_t)wtot);
    const bool useW8 = (off <= ws_size);
    if (!useW8) off = off_saved;

    char* w8p = (char*)d_ws;
    double* scales = (double*)(w8p + oScale);
    double* parts  = (double*)(w8p + oPart);
    double *SM1=(double*)(w8p+oSM1), *SM2=(double*)(w8p+oSM2), *SM3=(double*)(w8p+oSM3);
    double *CB=(double*)(w8p+oCB), *MOD=(double*)(w8p+oMOD);
    double *H=(double*)(w8p+oH), *INT=(double*)(w8p+oINT);
    double *F0=(double*)(w8p+oF0), *XT=(double*)(w8p+oXT);
    double *FB=(double*)(w8p+oFB), *IB=(double*)(w8p+oIB), *GB=(double*)(w8p+oGB);
    double *ACC=F0, *OB=H, *RO=(double*)(w8p+oRO);
    signed char *Q8X=(signed char*)(w8p+oQ8X), *Q8I=(signed char*)(w8p+oQ8I);
    signed char *Q8O=(signed char*)(w8p+oQ8O), *Q8R=(signed char*)(w8p+oQ8R);
    signed char *Q8T=(signed char*)(w8p+oQ8T), *Q8C=(signed char*)(w8p+oQ8C);
    double *DSX=(double*)(w8p+oDSX), *DSI=(double*)(w8p+oDSI), *DSO=(double*)(w8p+oDSO);
    double *DSR=(double*)(w8p+oDSR), *DST=(double*)(w8p+oDST), *DSC=(double*)(w8p+oDSC);
    signed char* W8 = (signed char*)(w8p + oW8);

    // ---------- weight scales (+ one-time ternarize) ----------
    k_abssum_all<<<dim3(32,37), 256, 0, stream>>>(wl, parts);
    k_abssum_fin<<<37, 64, 0, stream>>>(parts, scales);
    if (useW8)
        k_ternarize<<<dim3(64,37), 256, 0, stream>>>(wl, wo, scales, W8);

    // ---------- launch helpers ----------
    auto qgemm = [&](const signed char* A8, const double* as, const float* Win, int slot,
                     const float* b, double* Cout, int M, int N, int K, int accum){
        dim3 g((unsigned)((M+127)/128), (unsigned)((N+127)/128));
        if (useW8)
            k_qgemm<0,1><<<g, 256, 0, stream>>>(A8, as, Win, W8 + wo.o[slot],
                                                scales+slot, wn[slot], b, Cout, M, N, K, accum);
        else
            k_qgemm<0,0><<<g, 256, 0, stream>>>(A8, as, Win, nullptr,
                                                scales+slot, wn[slot], b, Cout, M, N, K, accum);
    };
    auto qgemmGate = [&](const signed char* A8, const double* as, const float* Win, int slot,
                         double* Cout, int M){
        dim3 g((unsigned)((M+127)/128), 36u);
        if (useW8)
            k_qgemm<1,1><<<g, 256, 0, stream>>>(A8, as, Win, W8 + wo.o[slot],
                                                scales+slot, wn[slot], nullptr, Cout, M, 4608, 1152, 0);
        else
            k_qgemm<1,0><<<g, 256, 0, stream>>>(A8, as, Win, nullptr,
                                                scales+slot, wn[slot], nullptr, Cout, M, 4608, 1152, 0);
    };

    // ---------- conditioning vector c ----------
    k_temb<<<8, 128, 0, stream>>>(T, SM1);
    k_rsq8<double><<<8, 256, 256*8, stream>>>(SM1, Q8T, DST, 256, 0);
    qgemm(Q8T, DST, te_w1, 0, te_b1, SM3, 8, 1152, 256, 0);
    k_rsq8<double><<<8, 256, 1152*8, stream>>>(SM3, Q8T, DST, 1152, 1);
    qgemm(Q8T, DST, te_w2, 1, te_b2, SM2, 8, 1152, 1152, 0);
    k_rsq8<float><<<8, 256, 768*8, stream>>>(Y, Q8T, DST, 768, 0);
    qgemm(Q8T, DST, pp_w, 2, pp_b, SM3, 8, 1152, 768, 0);
    k_add<<<36, 256, 0, stream>>>(SM2, SM3, CB, 9216);
    k_rsq8<double><<<8, 256, 1152*8, stream>>>(CB, Q8C, DSC, 1152, 1);

    // ---------- spatial adapter: patch embed + block 0 only ----------
    k_dgemm<1,0><<<dim3(18,128), 256, 0, stream>>>(XC, sa_pe_w, sa_pe_b, H, 8192, 1152, 1536);
    for (int ch = 0; ch < 8; ++ch) {
        double* Hrow = H + (size_t)ch*1024*1152;
        k_lnq8<<<1024, 256, 1152*8, stream>>>(Hrow, Q8X, DSX, 1152, sa_ln_g, sa_ln_b,
                                              nullptr, nullptr, 0, 1e-5);
        qgemmGate(Q8X, DSX, sa_gate_w, 3, INT, 1024);
        k_rsq8<double><<<1024, 256, 4608*8, stream>>>(INT, Q8I, DSI, 4608, 0);
        qgemm(Q8I, DSI, sa_down_w, 4, nullptr, Hrow, 1024, 1152, 4608, 0);
    }
    k_dgemm<2,1><<<dim3(18,32), 256, 0, stream>>>(H, sa_dc_w, sa_dc_b, F0, 2048, 1152, 4608);

    // ---------- patchify latents + pos + feats0 ----------
    k_patchify<<<9216, 256, 0, stream>>>(X, xe_w, xe_b, pos, F0, XT);
    k_rsq8<float><<<512, 256, 1152*8, stream>>>(REF, Q8R, DSR, 1152, 0);

    // ---------- transformer blocks (OB aliases dead H) ----------
    for (int l = 0; l < 2; ++l) {
        int sb = 5 + l*15;
        const float *wada = ada_w + (size_t)l*7962624, *bada = ada_b + (size_t)l*6912;
        const float *swi = sa_wi + (size_t)l*1327104, *swf = sa_wf + (size_t)l*1327104;
        const float *swg = sa_wg + (size_t)l*1327104, *swo = sa_wo + (size_t)l*1327104;
        const float *mwi = mv_wi + (size_t)l*1327104, *mwf = mv_wf + (size_t)l*1327104;
        const float *mwg = mv_wg + (size_t)l*1327104, *mwo = mv_wo + (size_t)l*1327104;
        const float *rwi = rf_wi + (size_t)l*1327104, *rwf = rf_wf + (size_t)l*1327104;
        const float *rwg = rf_wg + (size_t)l*1327104, *rwo = rf_wo + (size_t)l*1327104;
        const float *wgt = gate_w + (size_t)l*10616832, *wdn = down_w + (size_t)l*5308416;

        qgemm(Q8C, DSC, wada, sb+0, bada, MOD, 8, 6912, 1152, 0);

        k_lnq8<<<2048, 256, 1152*8, stream>>>(XT, Q8X, DSX, 1152, nullptr, nullptr,
                                              MOD+0, MOD+1152, 6912, 1e-6);

        // self attention (seq = 256 tokens)
        qgemm(Q8X, DSX, swf, sb+2, nullptr, FB, 2048, 1152, 1152, 0);
        qgemm(Q8X, DSX, swi, sb+1, nullptr, IB, 2048, 1152, 1152, 0);
        qgemm(Q8X, DSX, swg, sb+3, nullptr, GB, 2048, 1152, 1152, 0);
        k_gatepre<<<9216, 256, 0, stream>>>(FB, IB, 2359296LL);
        k_scan2<<<36, 256, 0, stream>>>(FB, IB, OB, 8, 294912LL, 1152, 1152LL, 256);
        k_ogateq8<<<2048, 256, 1152*8, stream>>>(OB, GB, Q8O, DSO, 1152);
        qgemm(Q8O, DSO, swo, sb+4, nullptr, ACC, 2048, 1152, 1152, 0);

        // multi-view attention (seq = 4 views; token layout unchanged)
        qgemm(Q8X, DSX, mwf, sb+6, nullptr, FB, 2048, 1152, 1152, 0);
        qgemm(Q8X, DSX, mwi, sb+5, nullptr, IB, 2048, 1152, 1152, 0);
        qgemm(Q8X, DSX, mwg, sb+7, nullptr, GB, 2048, 1152, 1152, 0);
        k_gatepre<<<9216, 256, 0, stream>>>(FB, IB, 2359296LL);
        k_scan2<<<2304, 256, 0, stream>>>(FB, IB, OB, 2, 1179648LL, 294912, 294912LL, 4);
        k_ogateq8<<<2048, 256, 1152*8, stream>>>(OB, GB, Q8O, DSO, 1152);
        qgemm(Q8O, DSO, mwo, sb+8, nullptr, ACC, 2048, 1152, 1152, 1);   // +=

        // ref attention on 2 unique batches
        qgemm(Q8R, DSR, rwf, sb+10, nullptr, FB, 512, 1152, 1152, 0);
        qgemm(Q8R, DSR, rwi, sb+9,  nullptr, IB, 512, 1152, 1152, 0);
        qgemm(Q8R, DSR, rwg, sb+11, nullptr, GB, 512, 1152, 1152, 0);
        k_gatepre<<<2304, 256, 0, stream>>>(FB, IB, 589824LL);
        k_scan2<<<9, 256, 0, stream>>>(FB, IB, OB, 2, 294912LL, 1152, 1152LL, 256);
        k_ogateq8<<<512, 256, 1152*8, stream>>>(OB, GB, Q8O, DSO, 1152);
        qgemm(Q8O, DSO, rwo, sb+12, nullptr, RO, 512, 1152, 1152, 0);

        k_resid_attn<<<9216, 256, 0, stream>>>(XT, ACC, RO, MOD);

        // MLP (1024-row chunks through INT)
        k_lnq8<<<2048, 256, 1152*8, stream>>>(XT, Q8X, DSX, 1152, nullptr, nullptr,
                                              MOD+3*1152, MOD+4*1152, 6912, 1e-6);
        for (int ch = 0; ch < 2; ++ch) {
            qgemmGate(Q8X + (size_t)ch*1024*1152, DSX + ch*1024, wgt, sb+13, INT, 1024);
            k_rsq8<double><<<1024, 256, 4608*8, stream>>>(INT, Q8I, DSI, 4608, 0);
            qgemm(Q8I, DSI, wdn, sb+14, nullptr, OB + (size_t)ch*1024*1152, 1024, 1152, 4608, 0);
        }
        k_resid_mlp<<<9216, 256, 0, stream>>>(XT, OB, MOD);
    }

    // ---------- final layer + unpatchify ----------
    qgemm(Q8C, DSC, fl_ada_w, 35, fl_ada_b, MOD, 8, 2304, 1152, 0);
    k_lnq8<<<2048, 256, 1152*8, stream>>>(XT, Q8X, DSX, 1152, nullptr, nullptr,
                                          MOD+0, MOD+1152, 2304, 1e-6);
    qgemm(Q8X, DSX, fl_w, 36, fl_b, FB, 2048, 32, 1152, 0);
    k_unpatch<<<256, 256, 0, stream>>>(FB, OUT);
}